// Round 14
// baseline (345.287 us; speedup 1.0000x reference)
//
#include <hip/hip_runtime.h>
#include <hip/hip_fp16.h>

#define NN 100000
#define NE 3200000
#define NG 512
#define DIN 128
#define F1 32
#define F2 64
#define FC 96
#define NC 10
#define BNEPS 1e-5f
#define HALFN 50000

#define BSH 8                // bucket shift: 256 nodes/bucket
#define NBUK 391             // ceil(NN/256)
#define EPB 16384            // edges per block in hist/binwrite
#define NBLK 196             // ceil(NE/EPB)
#define SCAN_N (NBUK * NBLK) // 76636
#define SCAN_NB ((SCAN_N + 1023) / 1024)  // 75

typedef unsigned int uint;

__device__ __forceinline__ void atomAddF(float* p, float v) { unsafeAtomicAdd(p, v); }
__device__ __forceinline__ float2 h2f(uint u) {
  __half2 h = *reinterpret_cast<__half2*>(&u);
  return __half22float2(h);
}
__device__ __forceinline__ uint f2h2(float a, float b) {
  __half2 h = __floats2half2_rn(a, b);
  return *reinterpret_cast<uint*>(&h);
}

// ---- per-block bucket histogram ----
__global__ __launch_bounds__(256) void k_hist(const int* __restrict__ dst,
                                              unsigned* __restrict__ bhist) {
  __shared__ unsigned h[NBUK];
  int t = threadIdx.x, b = blockIdx.x;
  for (int i = t; i < NBUK; i += 256) h[i] = 0;
  __syncthreads();
  int beg = b * EPB, end = min(beg + EPB, NE);
  for (int e = beg + t; e < end; e += 256) atomicAdd(&h[dst[e] >> BSH], 1u);
  __syncthreads();
  for (int i = t; i < NBUK; i += 256) bhist[(size_t)i * NBLK + b] = h[i];
}

// ---- generic 3-phase exclusive scan (in place) ----
__global__ __launch_bounds__(256) void k_scan1(unsigned* __restrict__ data, int n,
                                               unsigned* __restrict__ bsum) {
  __shared__ unsigned ts[256];
  int b = blockIdx.x, t = threadIdx.x;
  int base = b * 1024 + t * 4;
  unsigned v0 = 0, v1 = 0, v2 = 0, v3 = 0;
  if (base + 3 < n) {
    uint4 u = *(const uint4*)&data[base];
    v0 = u.x; v1 = u.y; v2 = u.z; v3 = u.w;
  } else {
    if (base < n) v0 = data[base];
    if (base + 1 < n) v1 = data[base + 1];
    if (base + 2 < n) v2 = data[base + 2];
    if (base + 3 < n) v3 = data[base + 3];
  }
  unsigned s = v0 + v1 + v2 + v3;
  ts[t] = s;
  __syncthreads();
  for (int d = 1; d < 256; d <<= 1) {
    unsigned add = (t >= d) ? ts[t - d] : 0u;
    __syncthreads();
    ts[t] += add;
    __syncthreads();
  }
  unsigned run = ts[t] - s;
  if (t == 255) bsum[b] = ts[255];
  if (base < n) data[base] = run;
  run += v0;
  if (base + 1 < n) data[base + 1] = run;
  run += v1;
  if (base + 2 < n) data[base + 2] = run;
  run += v2;
  if (base + 3 < n) data[base + 3] = run;
}

__global__ void k_scan2(unsigned* __restrict__ bsum, int nb) {
  __shared__ unsigned ts[512];
  int t = threadIdx.x;
  unsigned v = (t < nb) ? bsum[t] : 0u;
  ts[t] = v;
  __syncthreads();
  for (int d = 1; d < 512; d <<= 1) {
    unsigned a = (t >= d) ? ts[t - d] : 0u;
    __syncthreads();
    ts[t] += a;
    __syncthreads();
  }
  if (t < nb) bsum[t] = ts[t] - v;
}

__global__ void k_scan3(unsigned* __restrict__ data, int n, const unsigned* __restrict__ bsum,
                        int total) {
  int i = blockIdx.x * 256 + threadIdx.x;
  if (i < n) data[i] += bsum[i >> 10];
  if (i == 0) data[n] = (unsigned)total;
}

// ---- bin-write: packed[pos] = (src<<8)|dstlo, grouped by bucket ----
__global__ __launch_bounds__(256) void k_binwrite(const int* __restrict__ src,
                                                  const int* __restrict__ dst,
                                                  const unsigned* __restrict__ offs2,
                                                  int* __restrict__ packed) {
  __shared__ unsigned cur[NBUK];
  int t = threadIdx.x, b = blockIdx.x;
  for (int i = t; i < NBUK; i += 256) cur[i] = offs2[(size_t)i * NBLK + b];
  __syncthreads();
  int beg = b * EPB, end = min(beg + EPB, NE);
  for (int e = beg + t; e < end; e += 256) {
    int d = dst[e];
    unsigned pos = atomicAdd(&cur[d >> BSH], 1u);
    packed[pos] = (src[e] << BSH) | (d & 255);
  }
}

// ---- bucket counting-sort with (dstlo, srchalf) key -> segmented CSR ----
// offs[2*node], offs[2*node+1] = start of src<HALFN and src>=HALFN segments
__global__ __launch_bounds__(256) void k_bsort(const int* __restrict__ packed,
                                               const unsigned* __restrict__ offs2,
                                               int* __restrict__ csr,
                                               int* __restrict__ offs,
                                               float* __restrict__ dinv) {
  int buk = blockIdx.x, t = threadIdx.x;
  __shared__ unsigned cnt[512];
  __shared__ int cur[512];
  __shared__ unsigned wsum[4];
  cnt[t] = 0;
  cnt[t + 256] = 0;
  __syncthreads();
  unsigned beg = offs2[(size_t)buk * NBLK], end = offs2[(size_t)(buk + 1) * NBLK];
  for (unsigned j = beg + t; j < end; j += 256) {
    int p = packed[j];
    int key = ((p & 255) << 1) | ((p >> BSH) >= HALFN ? 1 : 0);
    atomicAdd(&cnt[key], 1u);
  }
  __syncthreads();
  unsigned v0 = cnt[2 * t], v1 = cnt[2 * t + 1];
  unsigned s = v0 + v1;
  unsigned inc = s;
#pragma unroll
  for (int d = 1; d < 64; d <<= 1) {
    unsigned o = __shfl_up(inc, d, 64);
    if ((t & 63) >= d) inc += o;
  }
  int wv = t >> 6;
  if ((t & 63) == 63) wsum[wv] = inc;
  __syncthreads();
  unsigned woff = 0;
  for (int i = 0; i < wv; ++i) woff += wsum[i];
  unsigned ex = woff + inc - s;  // exclusive prefix over node pairs within bucket
  cur[2 * t] = (int)(beg + ex);
  cur[2 * t + 1] = (int)(beg + ex + v0);
  int node = (buk << BSH) + t;
  if (node < NN) {
    offs[2 * node] = (int)(beg + ex);
    offs[2 * node + 1] = (int)(beg + ex + v0);
    dinv[node] = rsqrtf((float)s + 1.0f);
  } else if (node == NN) {
    offs[2 * NN] = (int)(beg + ex);  // == NE
  }
  __syncthreads();
  for (unsigned j = beg + t; j < end; j += 256) {
    int p = packed[j];
    int key = ((p & 255) << 1) | ((p >> BSH) >= HALFN ? 1 : 0);
    int pos = atomicAdd(&cur[key], 1);
    csr[pos] = p >> BSH;
  }
}

// ---- graph boundaries from sorted batch ----
__global__ void k_gbound(const int* __restrict__ batch, int* __restrict__ gstart) {
  int i = blockIdx.x * 256 + threadIdx.x;
  if (i >= NN) return;
  int b = batch[i], p = i ? batch[i - 1] : -1;
  for (int g = p + 1; g <= b; ++g) gstart[g] = i;
  if (i == NN - 1)
    for (int g = b + 1; g <= NG; ++g) gstart[g] = NN;
}

// ---- gemm1: h1sh = fp16((x @ W1) * dinv)  [NN,128]@[128,32] ----
__global__ __launch_bounds__(256) void k_gemm1(const float* __restrict__ x,
                                               const float* __restrict__ W,
                                               const float* __restrict__ dinv,
                                               __half* __restrict__ h1sh) {
  __shared__ __align__(16) float Ws[DIN * F1];     // 16 KB, [k][c] row-major
  __shared__ __align__(16) float xs[64][DIN + 4];  // 33 KB
  int t = threadIdx.x;
  for (int i = t; i < DIN * F1 / 4; i += 256)
    *(float4*)&Ws[i * 4] = *(const float4*)&W[i * 4];
  int row0 = blockIdx.x * 64;
  for (int i = t; i < 64 * 32; i += 256) {
    int r = i >> 5, q = i & 31;
    int row = row0 + r;
    float4 v = (row < NN) ? *(const float4*)&x[(size_t)row * DIN + q * 4]
                          : make_float4(0.f, 0.f, 0.f, 0.f);
    *(float4*)&xs[r][q * 4] = v;
  }
  __syncthreads();
  int cg = t & 7, rg = t >> 3;   // 8 col-groups x 32 row-groups
  int c0 = cg * 4, r0 = rg * 2;
  float acc[2][4];
#pragma unroll
  for (int i = 0; i < 2; ++i)
#pragma unroll
    for (int j = 0; j < 4; ++j) acc[i][j] = 0.f;
#pragma unroll 4
  for (int k = 0; k < DIN; k += 4) {
    float4 xv0 = *(float4*)&xs[r0][k];
    float4 xv1 = *(float4*)&xs[r0 + 1][k];
    float4 wf[4];
#pragma unroll
    for (int m = 0; m < 4; ++m) wf[m] = *(float4*)&Ws[(k + m) * F1 + c0];
    const float* x0 = (const float*)&xv0;
    const float* x1 = (const float*)&xv1;
#pragma unroll
    for (int m = 0; m < 4; ++m) {
      const float* wp = (const float*)&wf[m];
#pragma unroll
      for (int j = 0; j < 4; ++j) {
        acc[0][j] += x0[m] * wp[j];
        acc[1][j] += x1[m] * wp[j];
      }
    }
  }
#pragma unroll
  for (int i = 0; i < 2; ++i) {
    int row = row0 + r0 + i;
    if (row < NN) {
      float dv = dinv[row];
      uint2 o;
      o.x = f2h2(acc[i][0] * dv, acc[i][1] * dv);
      o.y = f2h2(acc[i][2] * dv, acc[i][3] * dv);
      *(uint2*)&h1sh[(size_t)row * F1 + c0] = o;
    }
  }
}

// ---- segment gather helper: accumulate fp16 rows over [beg,end) ----
__device__ __forceinline__ void gath_seg(const ushort* __restrict__ hs,
                                         const int* __restrict__ csr,
                                         int beg, int end, int slot, int f4,
                                         float& ax, float& ay, float& az, float& aw) {
  int j = beg + slot;
  for (; j + 8 < end; j += 16) {
    int s0 = csr[j], s1 = csr[j + 8];
    uint2 u0 = *(const uint2*)&hs[(size_t)s0 * F1 + f4];
    uint2 u1 = *(const uint2*)&hs[(size_t)s1 * F1 + f4];
    float2 a0 = h2f(u0.x), b0 = h2f(u0.y), a1 = h2f(u1.x), b1 = h2f(u1.y);
    ax += a0.x + a1.x; ay += a0.y + a1.y;
    az += b0.x + b1.x; aw += b0.y + b1.y;
  }
  if (j < end) {
    int s0 = csr[j];
    uint2 u0 = *(const uint2*)&hs[(size_t)s0 * F1 + f4];
    float2 a0 = h2f(u0.x), b0 = h2f(u0.y);
    ax += a0.x; ay += a0.y; az += b0.x; aw += b0.y;
  }
}

// ---- gather1: x1 = dinv*(h1s[node]+sum h1s[src]) + b1 -> hcat[:,0:32] (f32)
//      x1sh = fp16(x1 * dinv). Two src-half segments for L2 residency.
__global__ __launch_bounds__(256) void k_gather1(const ushort* __restrict__ hs,
                                                 const int* __restrict__ offs,
                                                 const int* __restrict__ csr,
                                                 const float* __restrict__ dinv,
                                                 const float* __restrict__ bias,
                                                 float* __restrict__ out1,
                                                 uint* __restrict__ out2) {
  int node = blockIdx.x * 4 + (threadIdx.x >> 6);  // NN%4==0
  int lane = threadIdx.x & 63;
  int slot = lane >> 3, f4 = (lane & 7) * 4;
  int beg = offs[2 * node], mid = offs[2 * node + 1], end = offs[2 * node + 2];
  float ax = 0.f, ay = 0.f, az = 0.f, aw = 0.f;
  gath_seg(hs, csr, beg, mid, slot, f4, ax, ay, az, aw);
  gath_seg(hs, csr, mid, end, slot, f4, ax, ay, az, aw);
#pragma unroll
  for (int m = 8; m < 64; m <<= 1) {
    ax += __shfl_xor(ax, m, 64); ay += __shfl_xor(ay, m, 64);
    az += __shfl_xor(az, m, 64); aw += __shfl_xor(aw, m, 64);
  }
  if (slot == 0) {
    float dv = dinv[node];
    uint2 su = *(const uint2*)&hs[(size_t)node * F1 + f4];
    float2 sa = h2f(su.x), sb = h2f(su.y);
    float4 bb = *(const float4*)&bias[f4];
    float vx = dv * (sa.x + ax) + bb.x;
    float vy = dv * (sa.y + ay) + bb.y;
    float vz = dv * (sb.x + az) + bb.z;
    float vw = dv * (sb.y + aw) + bb.w;
    *(float4*)&out1[(size_t)node * FC + f4] = make_float4(vx, vy, vz, vw);
    uint2 o;
    o.x = f2h2(vx * dv, vy * dv);
    o.y = f2h2(vz * dv, vw * dv);
    *(uint2*)&out2[(size_t)node * 16 + (f4 >> 1)] = o;
  }
}

// ---- gather2 fused with W2 matvec: hcat[:,32:96] = (Shat*x1s_row) @ W2 + b2 (f32) ----
__global__ __launch_bounds__(256) void k_gather2f(const ushort* __restrict__ hs,
                                                  const int* __restrict__ offs,
                                                  const int* __restrict__ csr,
                                                  const float* __restrict__ dinv,
                                                  const float* __restrict__ W2,
                                                  const float* __restrict__ b2,
                                                  float* __restrict__ hcat) {
  __shared__ float rowbuf[4][F1];
  int wv = threadIdx.x >> 6;
  int node = blockIdx.x * 4 + wv;  // NN%4==0
  int lane = threadIdx.x & 63;
  int slot = lane >> 3, f4 = (lane & 7) * 4;
  int beg = offs[2 * node], mid = offs[2 * node + 1], end = offs[2 * node + 2];
  float ax = 0.f, ay = 0.f, az = 0.f, aw = 0.f;
  gath_seg(hs, csr, beg, mid, slot, f4, ax, ay, az, aw);
  gath_seg(hs, csr, mid, end, slot, f4, ax, ay, az, aw);
#pragma unroll
  for (int m = 8; m < 64; m <<= 1) {
    ax += __shfl_xor(ax, m, 64); ay += __shfl_xor(ay, m, 64);
    az += __shfl_xor(az, m, 64); aw += __shfl_xor(aw, m, 64);
  }
  if (slot == 0) {
    float dv = dinv[node];
    uint2 su = *(const uint2*)&hs[(size_t)node * F1 + f4];
    float2 sa = h2f(su.x), sb = h2f(su.y);
    *(float4*)&rowbuf[wv][f4] = make_float4(
        dv * (sa.x + ax), dv * (sa.y + ay),
        dv * (sb.x + az), dv * (sb.y + aw));
  }
  __syncthreads();
  const float* row = rowbuf[wv];
  float acc = b2[lane];
#pragma unroll
  for (int k = 0; k < F1; ++k) acc += row[k] * W2[k * F2 + lane];
  hcat[(size_t)node * FC + F1 + lane] = acc;
}

// ---- lin1 v5: 64x96 tile, K split into 2 chunks of 48 -> 32.5 KB LDS, 4 blocks/CU ----
__global__ __launch_bounds__(384) void k_lin1(const float* __restrict__ hcat,
                                              const float* __restrict__ W,
                                              const float* __restrict__ b,
                                              float* __restrict__ y,
                                              float* __restrict__ colsum,
                                              float* __restrict__ colsumsq) {
  __shared__ __align__(16) float lds[8128];  // 32.5 KB: sW[48][100] + sX[64][52]
  float* sW = lds;          // [48][100]
  float* sX = lds + 4800;   // [64][52]
  int t = threadIdx.x;
  int row0 = blockIdx.x * 64;
  int tx = t % 24, ty = t / 24;
  int c0 = tx * 4, r0 = ty * 4;
  float acc[4][4];
#pragma unroll
  for (int i = 0; i < 4; ++i)
#pragma unroll
    for (int j = 0; j < 4; ++j) acc[i][j] = 0.f;
#pragma unroll
  for (int kc = 0; kc < 2; ++kc) {
    for (int i = t; i < 48 * 24; i += 384) {
      int k = i / 24, cq = (i % 24) * 4;
      float4 v = *(const float4*)&W[(kc * 48 + k) * FC + cq];
      *(float4*)&sW[k * 100 + cq] = v;
    }
    for (int i = t; i < 64 * 12; i += 384) {
      int r = i / 12, q = (i % 12) * 4;
      int row = row0 + r;
      float4 v = (row < NN) ? *(const float4*)&hcat[(size_t)row * FC + kc * 48 + q]
                            : make_float4(0.f, 0.f, 0.f, 0.f);
      *(float4*)&sX[r * 52 + q] = v;
    }
    __syncthreads();
#pragma unroll 4
    for (int k0 = 0; k0 < 48; k0 += 4) {
      float4 xf[4], wf[4];
#pragma unroll
      for (int i = 0; i < 4; ++i) xf[i] = *(float4*)&sX[(r0 + i) * 52 + k0];
#pragma unroll
      for (int m = 0; m < 4; ++m) wf[m] = *(float4*)&sW[(k0 + m) * 100 + c0];
#pragma unroll
      for (int i = 0; i < 4; ++i) {
        const float* xp = (const float*)&xf[i];
#pragma unroll
        for (int m = 0; m < 4; ++m) {
          const float* wp = (const float*)&wf[m];
#pragma unroll
          for (int j = 0; j < 4; ++j) acc[i][j] += xp[m] * wp[j];
        }
      }
    }
    __syncthreads();
  }
  float4 bb = *(const float4*)&b[c0];
  const float* bp = (const float*)&bb;
  float colp[4] = {0.f, 0.f, 0.f, 0.f}, colq[4] = {0.f, 0.f, 0.f, 0.f};
#pragma unroll
  for (int i = 0; i < 4; ++i) {
    int row = row0 + r0 + i;
    if (row < NN) {
      float v0 = fmaxf(acc[i][0] + bp[0], 0.f);
      float v1 = fmaxf(acc[i][1] + bp[1], 0.f);
      float v2 = fmaxf(acc[i][2] + bp[2], 0.f);
      float v3 = fmaxf(acc[i][3] + bp[3], 0.f);
      *(float4*)&y[(size_t)row * FC + c0] = make_float4(v0, v1, v2, v3);
      colp[0] += v0; colp[1] += v1; colp[2] += v2; colp[3] += v3;
      colq[0] += v0 * v0; colq[1] += v1 * v1; colq[2] += v2 * v2; colq[3] += v3 * v3;
    }
  }
  float* ps = sW;
  float* pq = sW + 1536;
  *(float4*)&ps[ty * 96 + c0] = make_float4(colp[0], colp[1], colp[2], colp[3]);
  *(float4*)&pq[ty * 96 + c0] = make_float4(colq[0], colq[1], colq[2], colq[3]);
  __syncthreads();
  if (t < 96) {
    float s = 0.f, s2 = 0.f;
#pragma unroll
    for (int i = 0; i < 16; ++i) { s += ps[i * 96 + t]; s2 += pq[i * 96 + t]; }
    atomAddF(&colsum[t], s);
    atomAddF(&colsumsq[t], s2);
  }
}

// ---- per-graph max pool (batch sorted): 8 rows in flight, f32 y ----
__global__ __launch_bounds__(768) void k_pool(const float* __restrict__ y,
                                              const int* __restrict__ gstart,
                                              float* __restrict__ pooled) {
  int g = blockIdx.x, t = threadIdx.x;
  int c = t % FC, h = t / FC;  // h in 0..7
  int beg = gstart[g], end = gstart[g + 1];
  float m0 = 0.f, m1 = 0.f;
  int r = beg + h;
  for (; r + 8 < end; r += 16) {
    m0 = fmaxf(m0, y[(size_t)r * FC + c]);
    m1 = fmaxf(m1, y[(size_t)(r + 8) * FC + c]);
  }
  if (r < end) m0 = fmaxf(m0, y[(size_t)r * FC + c]);
  m0 = fmaxf(m0, m1);
  __shared__ float sh[8][FC];
  sh[h][c] = m0;
  __syncthreads();
  if (h == 0) {
    float m = sh[0][c];
#pragma unroll
    for (int i = 1; i < 8; ++i) m = fmaxf(m, sh[i][c]);
    pooled[(size_t)g * FC + c] = (end > beg) ? m : 0.f;
  }
}

// ---- BN-apply on pooled ----
__global__ void k_poolbn(const float* __restrict__ pooled, const float* __restrict__ colsum,
                         const float* __restrict__ colsumsq, const int* __restrict__ gstart,
                         const float* __restrict__ g1, const float* __restrict__ bt1,
                         float* __restrict__ pbn) {
  int idx = blockIdx.x * 256 + threadIdx.x;
  if (idx < NG * FC) {
    int g = idx / FC, c = idx % FC;
    float m = colsum[c] * (1.f / NN);
    float var = colsumsq[c] * (1.f / NN) - m * m;
    float rs = rsqrtf(var + BNEPS);
    float v = (gstart[g + 1] > gstart[g]) ? (g1[c] * (pooled[idx] - m) * rs + bt1[c]) : 0.f;
    pbn[idx] = v;
  }
}

// ---- small MLP block ----
__global__ __launch_bounds__(256) void k_mlp(const float* __restrict__ X, int ncol,
                                             const float* __restrict__ W,
                                             const float* __restrict__ b,
                                             const float* __restrict__ g,
                                             const float* __restrict__ bt,
                                             float* __restrict__ out) {
  int c = blockIdx.x, t = threadIdx.x;
  __shared__ float vals[NG];
  __shared__ float red[256], redq[256];
  __shared__ float wc[FC];
  if (t < FC) wc[t] = W[(size_t)t * ncol + c];
  __syncthreads();
  float psum = 0.f, psq = 0.f;
  for (int r = t; r < NG; r += 256) {
    float acc = b[c];
#pragma unroll
    for (int k = 0; k < FC; ++k) acc += X[(size_t)r * FC + k] * wc[k];
    float v = fmaxf(acc, 0.f);
    vals[r] = v;
    psum += v;
    psq += v * v;
  }
  red[t] = psum;
  redq[t] = psq;
  __syncthreads();
  for (int s = 128; s > 0; s >>= 1) {
    if (t < s) { red[t] += red[t + s]; redq[t] += redq[t + s]; }
    __syncthreads();
  }
  float m = red[0] * (1.f / NG);
  float var = redq[0] * (1.f / NG) - m * m;
  float rs = rsqrtf(var + BNEPS);
  float gg = g[c], bb = bt[c];
  for (int r = t; r < NG; r += 256) out[(size_t)r * ncol + c] = gg * (vals[r] - m) * rs + bb;
}

extern "C" void kernel_launch(void* const* d_in, const int* in_sizes, int n_in,
                              void* d_out, int out_size, void* d_ws, size_t ws_size,
                              hipStream_t stream) {
  const float* x    = (const float*)d_in[0];
  const int* ei     = (const int*)d_in[1];
  const int* src    = ei;
  const int* dst    = ei + NE;
  const int* batch  = (const int*)d_in[2];
  const float* W1   = (const float*)d_in[3];
  const float* b1   = (const float*)d_in[4];
  const float* W2   = (const float*)d_in[5];
  const float* b2   = (const float*)d_in[6];
  const float* l1W  = (const float*)d_in[7];
  const float* l1b  = (const float*)d_in[8];
  const float* l1g  = (const float*)d_in[9];
  const float* l1bt = (const float*)d_in[10];
  const float* m1W  = (const float*)d_in[11];
  const float* m1b  = (const float*)d_in[12];
  const float* m1g  = (const float*)d_in[13];
  const float* m1bt = (const float*)d_in[14];
  const float* m2W  = (const float*)d_in[15];
  const float* m2b  = (const float*)d_in[16];
  const float* m2g  = (const float*)d_in[17];
  const float* m2bt = (const float*)d_in[18];
  float* out = (float*)d_out;

  float* ws = (float*)d_ws;
  // layout (float indices, all 16B-aligned)
  const size_t o_csum   = 0;          // 128
  const size_t o_csq    = 128;        // 128  (memset 256 floats)
  const size_t o_dinv   = 256;        // 100352
  const size_t o_gstart = 100608;     // 520 (NG+1)
  const size_t o_offs   = 101128;     // 200008 (2*NN+1 ints)
  const size_t o_offs2  = 301136;     // 147456-wide region; pooled/pbn/h3 alias after bsort
  const size_t o_bsum   = 448592;     // 304
  const size_t o_packed = 448896;     // 3,200,000 ints  <- y(f32, 9.6M) aliases [packed, hcat)
  const size_t o_h1sh   = 3648896;    // 1,600,000 (NN*32 fp16)
  const size_t o_x1sh   = 5248896;    // 1,600,000 (NN*32 fp16)
  const size_t o_csr    = 6848896;    // 3,200,000 ints
  const size_t o_hcat   = 10048896;   // 9,600,000 -> total 19,648,896 floats (78.6 MB)

  float* csum     = ws + o_csum;
  float* csq      = ws + o_csq;
  float* dinv     = ws + o_dinv;
  int* gstart     = (int*)(ws + o_gstart);
  int* offs       = (int*)(ws + o_offs);
  unsigned* offs2 = (unsigned*)(ws + o_offs2);
  unsigned* bsum  = (unsigned*)(ws + o_bsum);
  int* packed     = (int*)(ws + o_packed);
  __half* h1sh    = (__half*)(ws + o_h1sh);
  uint* x1sh      = (uint*)(ws + o_x1sh);
  int* csr        = (int*)(ws + o_csr);
  float* hcat     = ws + o_hcat;
  float* y        = ws + o_packed;           // alias: packed/h1sh/x1sh/csr dead by lin1
  float* pooled   = ws + o_offs2;            // alias: offs2 dead after bsort
  float* pbn      = ws + o_offs2 + 49152;
  float* h3       = ws + o_offs2 + 98304;

  hipMemsetAsync(ws, 0, 256 * sizeof(float), stream);  // csum + csq

  k_hist<<<NBLK, 256, 0, stream>>>(dst, offs2);
  k_scan1<<<SCAN_NB, 256, 0, stream>>>(offs2, SCAN_N, bsum);
  k_scan2<<<1, 512, 0, stream>>>(bsum, SCAN_NB);
  k_scan3<<<(SCAN_N + 255) / 256, 256, 0, stream>>>(offs2, SCAN_N, bsum, NE);
  k_binwrite<<<NBLK, 256, 0, stream>>>(src, dst, offs2, packed);
  k_bsort<<<NBUK, 256, 0, stream>>>(packed, offs2, csr, offs, dinv);
  k_gbound<<<(NN + 255) / 256, 256, 0, stream>>>(batch, gstart);

  k_gemm1<<<(NN + 63) / 64, 256, 0, stream>>>(x, W1, dinv, h1sh);
  // gather1: x1 -> hcat[:,0:32] (+b1, f32); x1sh = fp16(x1*dinv)
  k_gather1<<<NN / 4, 256, 0, stream>>>((const ushort*)h1sh, offs, csr, dinv, b1, hcat, x1sh);
  // gather2+gemm2 fused: hcat[:,32:96] = (Shat*x1s)@W2 + b2
  k_gather2f<<<NN / 4, 256, 0, stream>>>((const ushort*)x1sh, offs, csr, dinv, W2, b2, hcat);

  k_lin1<<<(NN + 63) / 64, 384, 0, stream>>>(hcat, l1W, l1b, y, csum, csq);
  k_pool<<<NG, 768, 0, stream>>>(y, gstart, pooled);
  k_poolbn<<<(NG * FC + 255) / 256, 256, 0, stream>>>(pooled, csum, csq, gstart, l1g, l1bt, pbn);

  k_mlp<<<FC, 256, 0, stream>>>(pbn, FC, m1W, m1b, m1g, m1bt, h3);
  k_mlp<<<NC, 256, 0, stream>>>(h3, NC, m2W, m2b, m2g, m2bt, out);
}

// Round 15
// 312.375 us; speedup vs baseline: 1.1054x; 1.1054x over previous
//
#include <hip/hip_runtime.h>
#include <hip/hip_fp16.h>

#define NN 100000
#define NE 3200000
#define NG 512
#define DIN 128
#define F1 32
#define F2 64
#define FC 96
#define NC 10
#define BNEPS 1e-5f

#define BSH 8                // bucket shift: 256 nodes/bucket
#define NBUK 391             // ceil(NN/256)
#define EPB 16384            // edges per block in hist/binwrite
#define NBLK 196             // ceil(NE/EPB)
#define SCAN_N (NBUK * NBLK) // 76636
#define SCAN_NB ((SCAN_N + 1023) / 1024)  // 75

typedef unsigned int uint;

__device__ __forceinline__ void atomAddF(float* p, float v) { unsafeAtomicAdd(p, v); }
__device__ __forceinline__ float2 h2f(uint u) {
  __half2 h = *reinterpret_cast<__half2*>(&u);
  return __half22float2(h);
}
__device__ __forceinline__ uint f2h2(float a, float b) {
  __half2 h = __floats2half2_rn(a, b);
  return *reinterpret_cast<uint*>(&h);
}

// ---- per-block bucket histogram (int4 edge reads) ----
__global__ __launch_bounds__(256) void k_hist(const int* __restrict__ dst,
                                              unsigned* __restrict__ bhist) {
  __shared__ unsigned h[NBUK];
  int t = threadIdx.x, b = blockIdx.x;
  for (int i = t; i < NBUK; i += 256) h[i] = 0;
  __syncthreads();
  int beg = b * EPB, end = min(beg + EPB, NE);
  for (int e = beg + t * 4; e < end; e += 1024) {
    int4 d4 = *(const int4*)&dst[e];
    atomicAdd(&h[d4.x >> BSH], 1u);
    atomicAdd(&h[d4.y >> BSH], 1u);
    atomicAdd(&h[d4.z >> BSH], 1u);
    atomicAdd(&h[d4.w >> BSH], 1u);
  }
  __syncthreads();
  for (int i = t; i < NBUK; i += 256) bhist[(size_t)i * NBLK + b] = h[i];
}

// ---- generic 3-phase exclusive scan (in place) ----
__global__ __launch_bounds__(256) void k_scan1(unsigned* __restrict__ data, int n,
                                               unsigned* __restrict__ bsum) {
  __shared__ unsigned ts[256];
  int b = blockIdx.x, t = threadIdx.x;
  int base = b * 1024 + t * 4;
  unsigned v0 = 0, v1 = 0, v2 = 0, v3 = 0;
  if (base + 3 < n) {
    uint4 u = *(const uint4*)&data[base];
    v0 = u.x; v1 = u.y; v2 = u.z; v3 = u.w;
  } else {
    if (base < n) v0 = data[base];
    if (base + 1 < n) v1 = data[base + 1];
    if (base + 2 < n) v2 = data[base + 2];
    if (base + 3 < n) v3 = data[base + 3];
  }
  unsigned s = v0 + v1 + v2 + v3;
  ts[t] = s;
  __syncthreads();
  for (int d = 1; d < 256; d <<= 1) {
    unsigned add = (t >= d) ? ts[t - d] : 0u;
    __syncthreads();
    ts[t] += add;
    __syncthreads();
  }
  unsigned run = ts[t] - s;
  if (t == 255) bsum[b] = ts[255];
  if (base < n) data[base] = run;
  run += v0;
  if (base + 1 < n) data[base + 1] = run;
  run += v1;
  if (base + 2 < n) data[base + 2] = run;
  run += v2;
  if (base + 3 < n) data[base + 3] = run;
}

__global__ void k_scan2(unsigned* __restrict__ bsum, int nb) {
  __shared__ unsigned ts[512];
  int t = threadIdx.x;
  unsigned v = (t < nb) ? bsum[t] : 0u;
  ts[t] = v;
  __syncthreads();
  for (int d = 1; d < 512; d <<= 1) {
    unsigned a = (t >= d) ? ts[t - d] : 0u;
    __syncthreads();
    ts[t] += a;
    __syncthreads();
  }
  if (t < nb) bsum[t] = ts[t] - v;
}

__global__ void k_scan3(unsigned* __restrict__ data, int n, const unsigned* __restrict__ bsum,
                        int total) {
  int i = blockIdx.x * 256 + threadIdx.x;
  if (i < n) data[i] += bsum[i >> 10];
  if (i == 0) data[n] = (unsigned)total;
}

// ---- bin-write: packed[pos] = (src<<8)|dstlo, grouped by bucket (int4 reads) ----
__global__ __launch_bounds__(256) void k_binwrite(const int* __restrict__ src,
                                                  const int* __restrict__ dst,
                                                  const unsigned* __restrict__ offs2,
                                                  int* __restrict__ packed) {
  __shared__ unsigned cur[NBUK];
  int t = threadIdx.x, b = blockIdx.x;
  for (int i = t; i < NBUK; i += 256) cur[i] = offs2[(size_t)i * NBLK + b];
  __syncthreads();
  int beg = b * EPB, end = min(beg + EPB, NE);
  for (int e = beg + t * 4; e < end; e += 1024) {
    int4 d4 = *(const int4*)&dst[e];
    int4 s4 = *(const int4*)&src[e];
    unsigned p0 = atomicAdd(&cur[d4.x >> BSH], 1u);
    packed[p0] = (s4.x << BSH) | (d4.x & 255);
    unsigned p1 = atomicAdd(&cur[d4.y >> BSH], 1u);
    packed[p1] = (s4.y << BSH) | (d4.y & 255);
    unsigned p2 = atomicAdd(&cur[d4.z >> BSH], 1u);
    packed[p2] = (s4.z << BSH) | (d4.z & 255);
    unsigned p3 = atomicAdd(&cur[d4.w >> BSH], 1u);
    packed[p3] = (s4.w << BSH) | (d4.w & 255);
  }
}

// ---- bucket counting-sort (256 nodes/bucket) -> per-node CSR + offs + dinv ----
__global__ __launch_bounds__(256) void k_bsort(const int* __restrict__ packed,
                                               const unsigned* __restrict__ offs2,
                                               int* __restrict__ csr,
                                               int* __restrict__ offs,
                                               float* __restrict__ dinv) {
  int buk = blockIdx.x, t = threadIdx.x;
  __shared__ unsigned cnt[256];
  __shared__ int cur[256];
  __shared__ unsigned wsum[4];
  cnt[t] = 0;
  __syncthreads();
  unsigned beg = offs2[(size_t)buk * NBLK], end = offs2[(size_t)(buk + 1) * NBLK];
  for (unsigned j = beg + t; j < end; j += 256) atomicAdd(&cnt[packed[j] & 255], 1u);
  __syncthreads();
  unsigned v = cnt[t];
  unsigned inc = v;
#pragma unroll
  for (int d = 1; d < 64; d <<= 1) {
    unsigned o = __shfl_up(inc, d, 64);
    if ((t & 63) >= d) inc += o;
  }
  int wv = t >> 6;
  if ((t & 63) == 63) wsum[wv] = inc;
  __syncthreads();
  unsigned woff = 0;
  for (int i = 0; i < wv; ++i) woff += wsum[i];
  unsigned ex = woff + inc - v;  // exclusive prefix within bucket
  cur[t] = (int)(beg + ex);
  int node = (buk << BSH) + t;
  if (node < NN) {
    offs[node] = (int)(beg + ex);
    dinv[node] = rsqrtf((float)v + 1.0f);
  } else if (node == NN) {
    offs[NN] = (int)(beg + ex);  // == NE
  }
  __syncthreads();
  for (unsigned j = beg + t; j < end; j += 256) {
    int p = packed[j];
    int pos = atomicAdd(&cur[p & 255], 1);
    csr[pos] = p >> BSH;
  }
}

// ---- graph boundaries from sorted batch ----
__global__ void k_gbound(const int* __restrict__ batch, int* __restrict__ gstart) {
  int i = blockIdx.x * 256 + threadIdx.x;
  if (i >= NN) return;
  int b = batch[i], p = i ? batch[i - 1] : -1;
  for (int g = p + 1; g <= b; ++g) gstart[g] = i;
  if (i == NN - 1)
    for (int g = b + 1; g <= NG; ++g) gstart[g] = NN;
}

// ---- gemm1: h1sh = fp16((x @ W1) * dinv)  [NN,128]@[128,32] ----
__global__ __launch_bounds__(256) void k_gemm1(const float* __restrict__ x,
                                               const float* __restrict__ W,
                                               const float* __restrict__ dinv,
                                               __half* __restrict__ h1sh) {
  __shared__ __align__(16) float Ws[DIN * F1];     // 16 KB, [k][c] row-major
  __shared__ __align__(16) float xs[64][DIN + 4];  // 33 KB
  int t = threadIdx.x;
  for (int i = t; i < DIN * F1 / 4; i += 256)
    *(float4*)&Ws[i * 4] = *(const float4*)&W[i * 4];
  int row0 = blockIdx.x * 64;
  for (int i = t; i < 64 * 32; i += 256) {
    int r = i >> 5, q = i & 31;
    int row = row0 + r;
    float4 v = (row < NN) ? *(const float4*)&x[(size_t)row * DIN + q * 4]
                          : make_float4(0.f, 0.f, 0.f, 0.f);
    *(float4*)&xs[r][q * 4] = v;
  }
  __syncthreads();
  int cg = t & 7, rg = t >> 3;   // 8 col-groups x 32 row-groups
  int c0 = cg * 4, r0 = rg * 2;
  float acc[2][4];
#pragma unroll
  for (int i = 0; i < 2; ++i)
#pragma unroll
    for (int j = 0; j < 4; ++j) acc[i][j] = 0.f;
#pragma unroll 4
  for (int k = 0; k < DIN; k += 4) {
    float4 xv0 = *(float4*)&xs[r0][k];
    float4 xv1 = *(float4*)&xs[r0 + 1][k];
    float4 wf[4];
#pragma unroll
    for (int m = 0; m < 4; ++m) wf[m] = *(float4*)&Ws[(k + m) * F1 + c0];
    const float* x0 = (const float*)&xv0;
    const float* x1 = (const float*)&xv1;
#pragma unroll
    for (int m = 0; m < 4; ++m) {
      const float* wp = (const float*)&wf[m];
#pragma unroll
      for (int j = 0; j < 4; ++j) {
        acc[0][j] += x0[m] * wp[j];
        acc[1][j] += x1[m] * wp[j];
      }
    }
  }
#pragma unroll
  for (int i = 0; i < 2; ++i) {
    int row = row0 + r0 + i;
    if (row < NN) {
      float dv = dinv[row];
      uint2 o;
      o.x = f2h2(acc[i][0] * dv, acc[i][1] * dv);
      o.y = f2h2(acc[i][2] * dv, acc[i][3] * dv);
      *(uint2*)&h1sh[(size_t)row * F1 + c0] = o;
    }
  }
}

// ---- gather core: 4-deep unrolled accumulate over [beg,end) ----
__device__ __forceinline__ void gath4(const ushort* __restrict__ hs,
                                      const int* __restrict__ csr,
                                      int beg, int end, int slot, int f4,
                                      float& ax, float& ay, float& az, float& aw) {
  int j = beg + slot;
  for (; j + 24 < end; j += 32) {
    int s0 = csr[j], s1 = csr[j + 8], s2 = csr[j + 16], s3 = csr[j + 24];
    uint2 u0 = *(const uint2*)&hs[(size_t)s0 * F1 + f4];
    uint2 u1 = *(const uint2*)&hs[(size_t)s1 * F1 + f4];
    uint2 u2 = *(const uint2*)&hs[(size_t)s2 * F1 + f4];
    uint2 u3 = *(const uint2*)&hs[(size_t)s3 * F1 + f4];
    float2 a0 = h2f(u0.x), b0 = h2f(u0.y), a1 = h2f(u1.x), b1 = h2f(u1.y);
    float2 a2 = h2f(u2.x), b2 = h2f(u2.y), a3 = h2f(u3.x), b3 = h2f(u3.y);
    ax += (a0.x + a1.x) + (a2.x + a3.x);
    ay += (a0.y + a1.y) + (a2.y + a3.y);
    az += (b0.x + b1.x) + (b2.x + b3.x);
    aw += (b0.y + b1.y) + (b2.y + b3.y);
  }
  for (; j < end; j += 8) {
    int s0 = csr[j];
    uint2 u0 = *(const uint2*)&hs[(size_t)s0 * F1 + f4];
    float2 a0 = h2f(u0.x), b0 = h2f(u0.y);
    ax += a0.x; ay += a0.y; az += b0.x; aw += b0.y;
  }
}

// ---- gather1: x1 = dinv*(h1s[node]+sum h1s[src]) + b1 -> hcat[:,0:32] (f32)
//      x1sh = fp16(x1 * dinv)
__global__ __launch_bounds__(256) void k_gather1(const ushort* __restrict__ hs,
                                                 const int* __restrict__ offs,
                                                 const int* __restrict__ csr,
                                                 const float* __restrict__ dinv,
                                                 const float* __restrict__ bias,
                                                 float* __restrict__ out1,
                                                 uint* __restrict__ out2) {
  int node = blockIdx.x * 4 + (threadIdx.x >> 6);  // NN%4==0
  int lane = threadIdx.x & 63;
  int slot = lane >> 3, f4 = (lane & 7) * 4;
  int beg = offs[node], end = offs[node + 1];
  float ax = 0.f, ay = 0.f, az = 0.f, aw = 0.f;
  gath4(hs, csr, beg, end, slot, f4, ax, ay, az, aw);
#pragma unroll
  for (int m = 8; m < 64; m <<= 1) {
    ax += __shfl_xor(ax, m, 64); ay += __shfl_xor(ay, m, 64);
    az += __shfl_xor(az, m, 64); aw += __shfl_xor(aw, m, 64);
  }
  if (slot == 0) {
    float dv = dinv[node];
    uint2 su = *(const uint2*)&hs[(size_t)node * F1 + f4];
    float2 sa = h2f(su.x), sb = h2f(su.y);
    float4 bb = *(const float4*)&bias[f4];
    float vx = dv * (sa.x + ax) + bb.x;
    float vy = dv * (sa.y + ay) + bb.y;
    float vz = dv * (sb.x + az) + bb.z;
    float vw = dv * (sb.y + aw) + bb.w;
    *(float4*)&out1[(size_t)node * FC + f4] = make_float4(vx, vy, vz, vw);
    uint2 o;
    o.x = f2h2(vx * dv, vy * dv);
    o.y = f2h2(vz * dv, vw * dv);
    *(uint2*)&out2[(size_t)node * 16 + (f4 >> 1)] = o;
  }
}

// ---- gather2 fused with W2 matvec: hcat[:,32:96] = (Shat*x1s_row) @ W2 + b2 (f32) ----
__global__ __launch_bounds__(256) void k_gather2f(const ushort* __restrict__ hs,
                                                  const int* __restrict__ offs,
                                                  const int* __restrict__ csr,
                                                  const float* __restrict__ dinv,
                                                  const float* __restrict__ W2,
                                                  const float* __restrict__ b2,
                                                  float* __restrict__ hcat) {
  __shared__ float rowbuf[4][F1];
  int wv = threadIdx.x >> 6;
  int node = blockIdx.x * 4 + wv;  // NN%4==0
  int lane = threadIdx.x & 63;
  int slot = lane >> 3, f4 = (lane & 7) * 4;
  int beg = offs[node], end = offs[node + 1];
  float ax = 0.f, ay = 0.f, az = 0.f, aw = 0.f;
  gath4(hs, csr, beg, end, slot, f4, ax, ay, az, aw);
#pragma unroll
  for (int m = 8; m < 64; m <<= 1) {
    ax += __shfl_xor(ax, m, 64); ay += __shfl_xor(ay, m, 64);
    az += __shfl_xor(az, m, 64); aw += __shfl_xor(aw, m, 64);
  }
  if (slot == 0) {
    float dv = dinv[node];
    uint2 su = *(const uint2*)&hs[(size_t)node * F1 + f4];
    float2 sa = h2f(su.x), sb = h2f(su.y);
    *(float4*)&rowbuf[wv][f4] = make_float4(
        dv * (sa.x + ax), dv * (sa.y + ay),
        dv * (sb.x + az), dv * (sb.y + aw));
  }
  __syncthreads();
  const float* row = rowbuf[wv];
  float acc = b2[lane];
#pragma unroll
  for (int k = 0; k < F1; ++k) acc += row[k] * W2[k * F2 + lane];
  hcat[(size_t)node * FC + F1 + lane] = acc;
}

// ---- lin1 v5: 64x96 tile, K split into 2 chunks of 48 -> 32.5 KB LDS, 4 blocks/CU ----
__global__ __launch_bounds__(384) void k_lin1(const float* __restrict__ hcat,
                                              const float* __restrict__ W,
                                              const float* __restrict__ b,
                                              float* __restrict__ y,
                                              float* __restrict__ colsum,
                                              float* __restrict__ colsumsq) {
  __shared__ __align__(16) float lds[8128];  // 32.5 KB: sW[48][100] + sX[64][52]
  float* sW = lds;          // [48][100]
  float* sX = lds + 4800;   // [64][52]
  int t = threadIdx.x;
  int row0 = blockIdx.x * 64;
  int tx = t % 24, ty = t / 24;
  int c0 = tx * 4, r0 = ty * 4;
  float acc[4][4];
#pragma unroll
  for (int i = 0; i < 4; ++i)
#pragma unroll
    for (int j = 0; j < 4; ++j) acc[i][j] = 0.f;
#pragma unroll
  for (int kc = 0; kc < 2; ++kc) {
    for (int i = t; i < 48 * 24; i += 384) {
      int k = i / 24, cq = (i % 24) * 4;
      float4 v = *(const float4*)&W[(kc * 48 + k) * FC + cq];
      *(float4*)&sW[k * 100 + cq] = v;
    }
    for (int i = t; i < 64 * 12; i += 384) {
      int r = i / 12, q = (i % 12) * 4;
      int row = row0 + r;
      float4 v = (row < NN) ? *(const float4*)&hcat[(size_t)row * FC + kc * 48 + q]
                            : make_float4(0.f, 0.f, 0.f, 0.f);
      *(float4*)&sX[r * 52 + q] = v;
    }
    __syncthreads();
#pragma unroll 4
    for (int k0 = 0; k0 < 48; k0 += 4) {
      float4 xf[4], wf[4];
#pragma unroll
      for (int i = 0; i < 4; ++i) xf[i] = *(float4*)&sX[(r0 + i) * 52 + k0];
#pragma unroll
      for (int m = 0; m < 4; ++m) wf[m] = *(float4*)&sW[(k0 + m) * 100 + c0];
#pragma unroll
      for (int i = 0; i < 4; ++i) {
        const float* xp = (const float*)&xf[i];
#pragma unroll
        for (int m = 0; m < 4; ++m) {
          const float* wp = (const float*)&wf[m];
#pragma unroll
          for (int j = 0; j < 4; ++j) acc[i][j] += xp[m] * wp[j];
        }
      }
    }
    __syncthreads();
  }
  float4 bb = *(const float4*)&b[c0];
  const float* bp = (const float*)&bb;
  float colp[4] = {0.f, 0.f, 0.f, 0.f}, colq[4] = {0.f, 0.f, 0.f, 0.f};
#pragma unroll
  for (int i = 0; i < 4; ++i) {
    int row = row0 + r0 + i;
    if (row < NN) {
      float v0 = fmaxf(acc[i][0] + bp[0], 0.f);
      float v1 = fmaxf(acc[i][1] + bp[1], 0.f);
      float v2 = fmaxf(acc[i][2] + bp[2], 0.f);
      float v3 = fmaxf(acc[i][3] + bp[3], 0.f);
      *(float4*)&y[(size_t)row * FC + c0] = make_float4(v0, v1, v2, v3);
      colp[0] += v0; colp[1] += v1; colp[2] += v2; colp[3] += v3;
      colq[0] += v0 * v0; colq[1] += v1 * v1; colq[2] += v2 * v2; colq[3] += v3 * v3;
    }
  }
  float* ps = sW;
  float* pq = sW + 1536;
  *(float4*)&ps[ty * 96 + c0] = make_float4(colp[0], colp[1], colp[2], colp[3]);
  *(float4*)&pq[ty * 96 + c0] = make_float4(colq[0], colq[1], colq[2], colq[3]);
  __syncthreads();
  if (t < 96) {
    float s = 0.f, s2 = 0.f;
#pragma unroll
    for (int i = 0; i < 16; ++i) { s += ps[i * 96 + t]; s2 += pq[i * 96 + t]; }
    atomAddF(&colsum[t], s);
    atomAddF(&colsumsq[t], s2);
  }
}

// ---- per-graph max pool (batch sorted): 8 rows in flight, f32 y ----
__global__ __launch_bounds__(768) void k_pool(const float* __restrict__ y,
                                              const int* __restrict__ gstart,
                                              float* __restrict__ pooled) {
  int g = blockIdx.x, t = threadIdx.x;
  int c = t % FC, h = t / FC;  // h in 0..7
  int beg = gstart[g], end = gstart[g + 1];
  float m0 = 0.f, m1 = 0.f;
  int r = beg + h;
  for (; r + 8 < end; r += 16) {
    m0 = fmaxf(m0, y[(size_t)r * FC + c]);
    m1 = fmaxf(m1, y[(size_t)(r + 8) * FC + c]);
  }
  if (r < end) m0 = fmaxf(m0, y[(size_t)r * FC + c]);
  m0 = fmaxf(m0, m1);
  __shared__ float sh[8][FC];
  sh[h][c] = m0;
  __syncthreads();
  if (h == 0) {
    float m = sh[0][c];
#pragma unroll
    for (int i = 1; i < 8; ++i) m = fmaxf(m, sh[i][c]);
    pooled[(size_t)g * FC + c] = (end > beg) ? m : 0.f;
  }
}

// ---- BN-apply on pooled ----
__global__ void k_poolbn(const float* __restrict__ pooled, const float* __restrict__ colsum,
                         const float* __restrict__ colsumsq, const int* __restrict__ gstart,
                         const float* __restrict__ g1, const float* __restrict__ bt1,
                         float* __restrict__ pbn) {
  int idx = blockIdx.x * 256 + threadIdx.x;
  if (idx < NG * FC) {
    int g = idx / FC, c = idx % FC;
    float m = colsum[c] * (1.f / NN);
    float var = colsumsq[c] * (1.f / NN) - m * m;
    float rs = rsqrtf(var + BNEPS);
    float v = (gstart[g + 1] > gstart[g]) ? (g1[c] * (pooled[idx] - m) * rs + bt1[c]) : 0.f;
    pbn[idx] = v;
  }
}

// ---- small MLP block ----
__global__ __launch_bounds__(256) void k_mlp(const float* __restrict__ X, int ncol,
                                             const float* __restrict__ W,
                                             const float* __restrict__ b,
                                             const float* __restrict__ g,
                                             const float* __restrict__ bt,
                                             float* __restrict__ out) {
  int c = blockIdx.x, t = threadIdx.x;
  __shared__ float vals[NG];
  __shared__ float red[256], redq[256];
  __shared__ float wc[FC];
  if (t < FC) wc[t] = W[(size_t)t * ncol + c];
  __syncthreads();
  float psum = 0.f, psq = 0.f;
  for (int r = t; r < NG; r += 256) {
    float acc = b[c];
#pragma unroll
    for (int k = 0; k < FC; ++k) acc += X[(size_t)r * FC + k] * wc[k];
    float v = fmaxf(acc, 0.f);
    vals[r] = v;
    psum += v;
    psq += v * v;
  }
  red[t] = psum;
  redq[t] = psq;
  __syncthreads();
  for (int s = 128; s > 0; s >>= 1) {
    if (t < s) { red[t] += red[t + s]; redq[t] += redq[t + s]; }
    __syncthreads();
  }
  float m = red[0] * (1.f / NG);
  float var = redq[0] * (1.f / NG) - m * m;
  float rs = rsqrtf(var + BNEPS);
  float gg = g[c], bb = bt[c];
  for (int r = t; r < NG; r += 256) out[(size_t)r * ncol + c] = gg * (vals[r] - m) * rs + bb;
}

extern "C" void kernel_launch(void* const* d_in, const int* in_sizes, int n_in,
                              void* d_out, int out_size, void* d_ws, size_t ws_size,
                              hipStream_t stream) {
  const float* x    = (const float*)d_in[0];
  const int* ei     = (const int*)d_in[1];
  const int* src    = ei;
  const int* dst    = ei + NE;
  const int* batch  = (const int*)d_in[2];
  const float* W1   = (const float*)d_in[3];
  const float* b1   = (const float*)d_in[4];
  const float* W2   = (const float*)d_in[5];
  const float* b2   = (const float*)d_in[6];
  const float* l1W  = (const float*)d_in[7];
  const float* l1b  = (const float*)d_in[8];
  const float* l1g  = (const float*)d_in[9];
  const float* l1bt = (const float*)d_in[10];
  const float* m1W  = (const float*)d_in[11];
  const float* m1b  = (const float*)d_in[12];
  const float* m1g  = (const float*)d_in[13];
  const float* m1bt = (const float*)d_in[14];
  const float* m2W  = (const float*)d_in[15];
  const float* m2b  = (const float*)d_in[16];
  const float* m2g  = (const float*)d_in[17];
  const float* m2bt = (const float*)d_in[18];
  float* out = (float*)d_out;

  float* ws = (float*)d_ws;
  // layout (float indices, all 16B-aligned) — R13 layout
  const size_t o_csum   = 0;          // 128
  const size_t o_csq    = 128;        // 128  (memset 256 floats)
  const size_t o_dinv   = 256;        // 100352
  const size_t o_gstart = 100608;     // 520 (NG+1)
  const size_t o_offs   = 101128;     // 100360 (NN+1 ints)
  const size_t o_offs2  = 201488;     // region 306352 wide; pooled/pbn/h3 alias later
  const size_t o_bsum   = 507840;     // 304
  const size_t o_packed = 508144;     // 3,200,000 ints  <- y(f32, 9.6M) aliases [packed, hcat)
  const size_t o_h1sh   = 3708144;    // 1,600,000 (NN*32 fp16)
  const size_t o_x1sh   = 5308144;    // 1,600,000 (NN*32 fp16)
  const size_t o_csr    = 6908144;    // 3,200,000 ints
  const size_t o_hcat   = 10108144;   // 9,600,000 -> total 19,708,144 floats (78.8 MB)

  float* csum     = ws + o_csum;
  float* csq      = ws + o_csq;
  float* dinv     = ws + o_dinv;
  int* gstart     = (int*)(ws + o_gstart);
  int* offs       = (int*)(ws + o_offs);
  unsigned* offs2 = (unsigned*)(ws + o_offs2);
  unsigned* bsum  = (unsigned*)(ws + o_bsum);
  int* packed     = (int*)(ws + o_packed);
  __half* h1sh    = (__half*)(ws + o_h1sh);
  uint* x1sh      = (uint*)(ws + o_x1sh);
  int* csr        = (int*)(ws + o_csr);
  float* hcat     = ws + o_hcat;
  float* y        = ws + o_packed;           // alias: packed/h1sh/x1sh/csr dead by lin1
  float* pooled   = ws + o_offs2;            // alias: offs2 dead after bsort
  float* pbn      = ws + o_offs2 + 49152;
  float* h3       = ws + o_offs2 + 98304;

  hipMemsetAsync(ws, 0, 256 * sizeof(float), stream);  // csum + csq

  k_hist<<<NBLK, 256, 0, stream>>>(dst, offs2);
  k_scan1<<<SCAN_NB, 256, 0, stream>>>(offs2, SCAN_N, bsum);
  k_scan2<<<1, 512, 0, stream>>>(bsum, SCAN_NB);
  k_scan3<<<(SCAN_N + 255) / 256, 256, 0, stream>>>(offs2, SCAN_N, bsum, NE);
  k_binwrite<<<NBLK, 256, 0, stream>>>(src, dst, offs2, packed);
  k_bsort<<<NBUK, 256, 0, stream>>>(packed, offs2, csr, offs, dinv);
  k_gbound<<<(NN + 255) / 256, 256, 0, stream>>>(batch, gstart);

  k_gemm1<<<(NN + 63) / 64, 256, 0, stream>>>(x, W1, dinv, h1sh);
  // gather1: x1 -> hcat[:,0:32] (+b1, f32); x1sh = fp16(x1*dinv)
  k_gather1<<<NN / 4, 256, 0, stream>>>((const ushort*)h1sh, offs, csr, dinv, b1, hcat, x1sh);
  // gather2+gemm2 fused: hcat[:,32:96] = (Shat*x1s)@W2 + b2
  k_gather2f<<<NN / 4, 256, 0, stream>>>((const ushort*)x1sh, offs, csr, dinv, W2, b2, hcat);

  k_lin1<<<(NN + 63) / 64, 384, 0, stream>>>(hcat, l1W, l1b, y, csum, csq);
  k_pool<<<NG, 768, 0, stream>>>(y, gstart, pooled);
  k_poolbn<<<(NG * FC + 255) / 256, 256, 0, stream>>>(pooled, csum, csq, gstart, l1g, l1bt, pbn);

  k_mlp<<<FC, 256, 0, stream>>>(pbn, FC, m1W, m1b, m1g, m1bt, h3);
  k_mlp<<<NC, 256, 0, stream>>>(h3, NC, m2W, m2b, m2g, m2bt, out);
}

// Round 16
// 312.345 us; speedup vs baseline: 1.1055x; 1.0001x over previous
//
#include <hip/hip_runtime.h>
#include <hip/hip_fp16.h>

#define NN 100000
#define NE 3200000
#define NG 512
#define DIN 128
#define F1 32
#define F2 64
#define FC 96
#define NC 10
#define BNEPS 1e-5f

#define BSH 8                // bucket shift: 256 nodes/bucket
#define NBUK 391             // ceil(NN/256)
#define EPB 16384            // edges per block in hist/binwrite
#define NBLK 196             // ceil(NE/EPB)
#define SCAN_N (NBUK * NBLK) // 76636
#define SCAN_NB ((SCAN_N + 1023) / 1024)  // 75

typedef unsigned int uint;

__device__ __forceinline__ void atomAddF(float* p, float v) { unsafeAtomicAdd(p, v); }
__device__ __forceinline__ float2 h2f(uint u) {
  __half2 h = *reinterpret_cast<__half2*>(&u);
  return __half22float2(h);
}
__device__ __forceinline__ uint f2h2(float a, float b) {
  __half2 h = __floats2half2_rn(a, b);
  return *reinterpret_cast<uint*>(&h);
}

// ---- per-block bucket histogram (int4 edge reads) ----
__global__ __launch_bounds__(256) void k_hist(const int* __restrict__ dst,
                                              unsigned* __restrict__ bhist) {
  __shared__ unsigned h[NBUK];
  int t = threadIdx.x, b = blockIdx.x;
  for (int i = t; i < NBUK; i += 256) h[i] = 0;
  __syncthreads();
  int beg = b * EPB, end = min(beg + EPB, NE);
  for (int e = beg + t * 4; e < end; e += 1024) {
    int4 d4 = *(const int4*)&dst[e];
    atomicAdd(&h[d4.x >> BSH], 1u);
    atomicAdd(&h[d4.y >> BSH], 1u);
    atomicAdd(&h[d4.z >> BSH], 1u);
    atomicAdd(&h[d4.w >> BSH], 1u);
  }
  __syncthreads();
  for (int i = t; i < NBUK; i += 256) bhist[(size_t)i * NBLK + b] = h[i];
}

// ---- generic 3-phase exclusive scan (in place) ----
__global__ __launch_bounds__(256) void k_scan1(unsigned* __restrict__ data, int n,
                                               unsigned* __restrict__ bsum) {
  __shared__ unsigned ts[256];
  int b = blockIdx.x, t = threadIdx.x;
  int base = b * 1024 + t * 4;
  unsigned v0 = 0, v1 = 0, v2 = 0, v3 = 0;
  if (base + 3 < n) {
    uint4 u = *(const uint4*)&data[base];
    v0 = u.x; v1 = u.y; v2 = u.z; v3 = u.w;
  } else {
    if (base < n) v0 = data[base];
    if (base + 1 < n) v1 = data[base + 1];
    if (base + 2 < n) v2 = data[base + 2];
    if (base + 3 < n) v3 = data[base + 3];
  }
  unsigned s = v0 + v1 + v2 + v3;
  ts[t] = s;
  __syncthreads();
  for (int d = 1; d < 256; d <<= 1) {
    unsigned add = (t >= d) ? ts[t - d] : 0u;
    __syncthreads();
    ts[t] += add;
    __syncthreads();
  }
  unsigned run = ts[t] - s;
  if (t == 255) bsum[b] = ts[255];
  if (base < n) data[base] = run;
  run += v0;
  if (base + 1 < n) data[base + 1] = run;
  run += v1;
  if (base + 2 < n) data[base + 2] = run;
  run += v2;
  if (base + 3 < n) data[base + 3] = run;
}

__global__ void k_scan2(unsigned* __restrict__ bsum, int nb) {
  __shared__ unsigned ts[512];
  int t = threadIdx.x;
  unsigned v = (t < nb) ? bsum[t] : 0u;
  ts[t] = v;
  __syncthreads();
  for (int d = 1; d < 512; d <<= 1) {
    unsigned a = (t >= d) ? ts[t - d] : 0u;
    __syncthreads();
    ts[t] += a;
    __syncthreads();
  }
  if (t < nb) bsum[t] = ts[t] - v;
}

__global__ void k_scan3(unsigned* __restrict__ data, int n, const unsigned* __restrict__ bsum,
                        int total) {
  int i = blockIdx.x * 256 + threadIdx.x;
  if (i < n) data[i] += bsum[i >> 10];
  if (i == 0) data[n] = (unsigned)total;
}

// ---- bin-write: packed[pos] = (src<<8)|dstlo, grouped by bucket (int4 reads) ----
__global__ __launch_bounds__(256) void k_binwrite(const int* __restrict__ src,
                                                  const int* __restrict__ dst,
                                                  const unsigned* __restrict__ offs2,
                                                  int* __restrict__ packed) {
  __shared__ unsigned cur[NBUK];
  int t = threadIdx.x, b = blockIdx.x;
  for (int i = t; i < NBUK; i += 256) cur[i] = offs2[(size_t)i * NBLK + b];
  __syncthreads();
  int beg = b * EPB, end = min(beg + EPB, NE);
  for (int e = beg + t * 4; e < end; e += 1024) {
    int4 d4 = *(const int4*)&dst[e];
    int4 s4 = *(const int4*)&src[e];
    unsigned p0 = atomicAdd(&cur[d4.x >> BSH], 1u);
    packed[p0] = (s4.x << BSH) | (d4.x & 255);
    unsigned p1 = atomicAdd(&cur[d4.y >> BSH], 1u);
    packed[p1] = (s4.y << BSH) | (d4.y & 255);
    unsigned p2 = atomicAdd(&cur[d4.z >> BSH], 1u);
    packed[p2] = (s4.z << BSH) | (d4.z & 255);
    unsigned p3 = atomicAdd(&cur[d4.w >> BSH], 1u);
    packed[p3] = (s4.w << BSH) | (d4.w & 255);
  }
}

// ---- bucket counting-sort (256 nodes/bucket) -> per-node CSR + offs + dinv ----
__global__ __launch_bounds__(256) void k_bsort(const int* __restrict__ packed,
                                               const unsigned* __restrict__ offs2,
                                               int* __restrict__ csr,
                                               int* __restrict__ offs,
                                               float* __restrict__ dinv) {
  int buk = blockIdx.x, t = threadIdx.x;
  __shared__ unsigned cnt[256];
  __shared__ int cur[256];
  __shared__ unsigned wsum[4];
  cnt[t] = 0;
  __syncthreads();
  unsigned beg = offs2[(size_t)buk * NBLK], end = offs2[(size_t)(buk + 1) * NBLK];
  for (unsigned j = beg + t; j < end; j += 256) atomicAdd(&cnt[packed[j] & 255], 1u);
  __syncthreads();
  unsigned v = cnt[t];
  unsigned inc = v;
#pragma unroll
  for (int d = 1; d < 64; d <<= 1) {
    unsigned o = __shfl_up(inc, d, 64);
    if ((t & 63) >= d) inc += o;
  }
  int wv = t >> 6;
  if ((t & 63) == 63) wsum[wv] = inc;
  __syncthreads();
  unsigned woff = 0;
  for (int i = 0; i < wv; ++i) woff += wsum[i];
  unsigned ex = woff + inc - v;  // exclusive prefix within bucket
  cur[t] = (int)(beg + ex);
  int node = (buk << BSH) + t;
  if (node < NN) {
    offs[node] = (int)(beg + ex);
    dinv[node] = rsqrtf((float)v + 1.0f);
  } else if (node == NN) {
    offs[NN] = (int)(beg + ex);  // == NE
  }
  __syncthreads();
  for (unsigned j = beg + t; j < end; j += 256) {
    int p = packed[j];
    int pos = atomicAdd(&cur[p & 255], 1);
    csr[pos] = p >> BSH;
  }
}

// ---- graph boundaries from sorted batch ----
__global__ void k_gbound(const int* __restrict__ batch, int* __restrict__ gstart) {
  int i = blockIdx.x * 256 + threadIdx.x;
  if (i >= NN) return;
  int b = batch[i], p = i ? batch[i - 1] : -1;
  for (int g = p + 1; g <= b; ++g) gstart[g] = i;
  if (i == NN - 1)
    for (int g = b + 1; g <= NG; ++g) gstart[g] = NN;
}

// ---- gemm1: h1sh = fp16((x @ W1) * dinv)  [NN,128]@[128,32] ----
__global__ __launch_bounds__(256) void k_gemm1(const float* __restrict__ x,
                                               const float* __restrict__ W,
                                               const float* __restrict__ dinv,
                                               __half* __restrict__ h1sh) {
  __shared__ __align__(16) float Ws[DIN * F1];     // 16 KB, [k][c] row-major
  __shared__ __align__(16) float xs[64][DIN + 4];  // 33 KB
  int t = threadIdx.x;
  for (int i = t; i < DIN * F1 / 4; i += 256)
    *(float4*)&Ws[i * 4] = *(const float4*)&W[i * 4];
  int row0 = blockIdx.x * 64;
  for (int i = t; i < 64 * 32; i += 256) {
    int r = i >> 5, q = i & 31;
    int row = row0 + r;
    float4 v = (row < NN) ? *(const float4*)&x[(size_t)row * DIN + q * 4]
                          : make_float4(0.f, 0.f, 0.f, 0.f);
    *(float4*)&xs[r][q * 4] = v;
  }
  __syncthreads();
  int cg = t & 7, rg = t >> 3;   // 8 col-groups x 32 row-groups
  int c0 = cg * 4, r0 = rg * 2;
  float acc[2][4];
#pragma unroll
  for (int i = 0; i < 2; ++i)
#pragma unroll
    for (int j = 0; j < 4; ++j) acc[i][j] = 0.f;
#pragma unroll 4
  for (int k = 0; k < DIN; k += 4) {
    float4 xv0 = *(float4*)&xs[r0][k];
    float4 xv1 = *(float4*)&xs[r0 + 1][k];
    float4 wf[4];
#pragma unroll
    for (int m = 0; m < 4; ++m) wf[m] = *(float4*)&Ws[(k + m) * F1 + c0];
    const float* x0 = (const float*)&xv0;
    const float* x1 = (const float*)&xv1;
#pragma unroll
    for (int m = 0; m < 4; ++m) {
      const float* wp = (const float*)&wf[m];
#pragma unroll
      for (int j = 0; j < 4; ++j) {
        acc[0][j] += x0[m] * wp[j];
        acc[1][j] += x1[m] * wp[j];
      }
    }
  }
#pragma unroll
  for (int i = 0; i < 2; ++i) {
    int row = row0 + r0 + i;
    if (row < NN) {
      float dv = dinv[row];
      uint2 o;
      o.x = f2h2(acc[i][0] * dv, acc[i][1] * dv);
      o.y = f2h2(acc[i][2] * dv, acc[i][3] * dv);
      *(uint2*)&h1sh[(size_t)row * F1 + c0] = o;
    }
  }
}

// ---- gather core: 4-deep unrolled accumulate over [beg,end) ----
__device__ __forceinline__ void gath4(const ushort* __restrict__ hs,
                                      const int* __restrict__ csr,
                                      int beg, int end, int slot, int f4,
                                      float& ax, float& ay, float& az, float& aw) {
  int j = beg + slot;
  for (; j + 24 < end; j += 32) {
    int s0 = csr[j], s1 = csr[j + 8], s2 = csr[j + 16], s3 = csr[j + 24];
    uint2 u0 = *(const uint2*)&hs[(size_t)s0 * F1 + f4];
    uint2 u1 = *(const uint2*)&hs[(size_t)s1 * F1 + f4];
    uint2 u2 = *(const uint2*)&hs[(size_t)s2 * F1 + f4];
    uint2 u3 = *(const uint2*)&hs[(size_t)s3 * F1 + f4];
    float2 a0 = h2f(u0.x), b0 = h2f(u0.y), a1 = h2f(u1.x), b1 = h2f(u1.y);
    float2 a2 = h2f(u2.x), b2 = h2f(u2.y), a3 = h2f(u3.x), b3 = h2f(u3.y);
    ax += (a0.x + a1.x) + (a2.x + a3.x);
    ay += (a0.y + a1.y) + (a2.y + a3.y);
    az += (b0.x + b1.x) + (b2.x + b3.x);
    aw += (b0.y + b1.y) + (b2.y + b3.y);
  }
  for (; j < end; j += 8) {
    int s0 = csr[j];
    uint2 u0 = *(const uint2*)&hs[(size_t)s0 * F1 + f4];
    float2 a0 = h2f(u0.x), b0 = h2f(u0.y);
    ax += a0.x; ay += a0.y; az += b0.x; aw += b0.y;
  }
}

// ---- gather1: x1 = dinv*(h1s[node]+sum h1s[src]) + b1 -> hcat[:,0:32] (f32)
//      x1sh = fp16(x1 * dinv)
__global__ __launch_bounds__(256) void k_gather1(const ushort* __restrict__ hs,
                                                 const int* __restrict__ offs,
                                                 const int* __restrict__ csr,
                                                 const float* __restrict__ dinv,
                                                 const float* __restrict__ bias,
                                                 float* __restrict__ out1,
                                                 uint* __restrict__ out2) {
  int node = blockIdx.x * 4 + (threadIdx.x >> 6);  // NN%4==0
  int lane = threadIdx.x & 63;
  int slot = lane >> 3, f4 = (lane & 7) * 4;
  int beg = offs[node], end = offs[node + 1];
  float ax = 0.f, ay = 0.f, az = 0.f, aw = 0.f;
  gath4(hs, csr, beg, end, slot, f4, ax, ay, az, aw);
#pragma unroll
  for (int m = 8; m < 64; m <<= 1) {
    ax += __shfl_xor(ax, m, 64); ay += __shfl_xor(ay, m, 64);
    az += __shfl_xor(az, m, 64); aw += __shfl_xor(aw, m, 64);
  }
  if (slot == 0) {
    float dv = dinv[node];
    uint2 su = *(const uint2*)&hs[(size_t)node * F1 + f4];
    float2 sa = h2f(su.x), sb = h2f(su.y);
    float4 bb = *(const float4*)&bias[f4];
    float vx = dv * (sa.x + ax) + bb.x;
    float vy = dv * (sa.y + ay) + bb.y;
    float vz = dv * (sb.x + az) + bb.z;
    float vw = dv * (sb.y + aw) + bb.w;
    *(float4*)&out1[(size_t)node * FC + f4] = make_float4(vx, vy, vz, vw);
    uint2 o;
    o.x = f2h2(vx * dv, vy * dv);
    o.y = f2h2(vz * dv, vw * dv);
    *(uint2*)&out2[(size_t)node * 16 + (f4 >> 1)] = o;
  }
}

// ---- gather2 fused with W2 matvec: hcat[:,32:96] = (Shat*x1s_row) @ W2 + b2 (f32) ----
__global__ __launch_bounds__(256) void k_gather2f(const ushort* __restrict__ hs,
                                                  const int* __restrict__ offs,
                                                  const int* __restrict__ csr,
                                                  const float* __restrict__ dinv,
                                                  const float* __restrict__ W2,
                                                  const float* __restrict__ b2,
                                                  float* __restrict__ hcat) {
  __shared__ float rowbuf[4][F1];
  int wv = threadIdx.x >> 6;
  int node = blockIdx.x * 4 + wv;  // NN%4==0
  int lane = threadIdx.x & 63;
  int slot = lane >> 3, f4 = (lane & 7) * 4;
  int beg = offs[node], end = offs[node + 1];
  float ax = 0.f, ay = 0.f, az = 0.f, aw = 0.f;
  gath4(hs, csr, beg, end, slot, f4, ax, ay, az, aw);
#pragma unroll
  for (int m = 8; m < 64; m <<= 1) {
    ax += __shfl_xor(ax, m, 64); ay += __shfl_xor(ay, m, 64);
    az += __shfl_xor(az, m, 64); aw += __shfl_xor(aw, m, 64);
  }
  if (slot == 0) {
    float dv = dinv[node];
    uint2 su = *(const uint2*)&hs[(size_t)node * F1 + f4];
    float2 sa = h2f(su.x), sb = h2f(su.y);
    *(float4*)&rowbuf[wv][f4] = make_float4(
        dv * (sa.x + ax), dv * (sa.y + ay),
        dv * (sb.x + az), dv * (sb.y + aw));
  }
  __syncthreads();
  const float* row = rowbuf[wv];
  float acc = b2[lane];
#pragma unroll
  for (int k = 0; k < F1; ++k) acc += row[k] * W2[k * F2 + lane];
  hcat[(size_t)node * FC + F1 + lane] = acc;
}

// ---- lin1 v5: 64x96 tile, K split into 2 chunks of 48 -> 32.5 KB LDS, 4 blocks/CU ----
__global__ __launch_bounds__(384) void k_lin1(const float* __restrict__ hcat,
                                              const float* __restrict__ W,
                                              const float* __restrict__ b,
                                              float* __restrict__ y,
                                              float* __restrict__ colsum,
                                              float* __restrict__ colsumsq) {
  __shared__ __align__(16) float lds[8128];  // 32.5 KB: sW[48][100] + sX[64][52]
  float* sW = lds;          // [48][100]
  float* sX = lds + 4800;   // [64][52]
  int t = threadIdx.x;
  int row0 = blockIdx.x * 64;
  int tx = t % 24, ty = t / 24;
  int c0 = tx * 4, r0 = ty * 4;
  float acc[4][4];
#pragma unroll
  for (int i = 0; i < 4; ++i)
#pragma unroll
    for (int j = 0; j < 4; ++j) acc[i][j] = 0.f;
#pragma unroll
  for (int kc = 0; kc < 2; ++kc) {
    for (int i = t; i < 48 * 24; i += 384) {
      int k = i / 24, cq = (i % 24) * 4;
      float4 v = *(const float4*)&W[(kc * 48 + k) * FC + cq];
      *(float4*)&sW[k * 100 + cq] = v;
    }
    for (int i = t; i < 64 * 12; i += 384) {
      int r = i / 12, q = (i % 12) * 4;
      int row = row0 + r;
      float4 v = (row < NN) ? *(const float4*)&hcat[(size_t)row * FC + kc * 48 + q]
                            : make_float4(0.f, 0.f, 0.f, 0.f);
      *(float4*)&sX[r * 52 + q] = v;
    }
    __syncthreads();
#pragma unroll 4
    for (int k0 = 0; k0 < 48; k0 += 4) {
      float4 xf[4], wf[4];
#pragma unroll
      for (int i = 0; i < 4; ++i) xf[i] = *(float4*)&sX[(r0 + i) * 52 + k0];
#pragma unroll
      for (int m = 0; m < 4; ++m) wf[m] = *(float4*)&sW[(k0 + m) * 100 + c0];
#pragma unroll
      for (int i = 0; i < 4; ++i) {
        const float* xp = (const float*)&xf[i];
#pragma unroll
        for (int m = 0; m < 4; ++m) {
          const float* wp = (const float*)&wf[m];
#pragma unroll
          for (int j = 0; j < 4; ++j) acc[i][j] += xp[m] * wp[j];
        }
      }
    }
    __syncthreads();
  }
  float4 bb = *(const float4*)&b[c0];
  const float* bp = (const float*)&bb;
  float colp[4] = {0.f, 0.f, 0.f, 0.f}, colq[4] = {0.f, 0.f, 0.f, 0.f};
#pragma unroll
  for (int i = 0; i < 4; ++i) {
    int row = row0 + r0 + i;
    if (row < NN) {
      float v0 = fmaxf(acc[i][0] + bp[0], 0.f);
      float v1 = fmaxf(acc[i][1] + bp[1], 0.f);
      float v2 = fmaxf(acc[i][2] + bp[2], 0.f);
      float v3 = fmaxf(acc[i][3] + bp[3], 0.f);
      *(float4*)&y[(size_t)row * FC + c0] = make_float4(v0, v1, v2, v3);
      colp[0] += v0; colp[1] += v1; colp[2] += v2; colp[3] += v3;
      colq[0] += v0 * v0; colq[1] += v1 * v1; colq[2] += v2 * v2; colq[3] += v3 * v3;
    }
  }
  float* ps = sW;
  float* pq = sW + 1536;
  *(float4*)&ps[ty * 96 + c0] = make_float4(colp[0], colp[1], colp[2], colp[3]);
  *(float4*)&pq[ty * 96 + c0] = make_float4(colq[0], colq[1], colq[2], colq[3]);
  __syncthreads();
  if (t < 96) {
    float s = 0.f, s2 = 0.f;
#pragma unroll
    for (int i = 0; i < 16; ++i) { s += ps[i * 96 + t]; s2 += pq[i * 96 + t]; }
    atomAddF(&colsum[t], s);
    atomAddF(&colsumsq[t], s2);
  }
}

// ---- per-graph max pool (batch sorted): 8 rows in flight, f32 y ----
__global__ __launch_bounds__(768) void k_pool(const float* __restrict__ y,
                                              const int* __restrict__ gstart,
                                              float* __restrict__ pooled) {
  int g = blockIdx.x, t = threadIdx.x;
  int c = t % FC, h = t / FC;  // h in 0..7
  int beg = gstart[g], end = gstart[g + 1];
  float m0 = 0.f, m1 = 0.f;
  int r = beg + h;
  for (; r + 8 < end; r += 16) {
    m0 = fmaxf(m0, y[(size_t)r * FC + c]);
    m1 = fmaxf(m1, y[(size_t)(r + 8) * FC + c]);
  }
  if (r < end) m0 = fmaxf(m0, y[(size_t)r * FC + c]);
  m0 = fmaxf(m0, m1);
  __shared__ float sh[8][FC];
  sh[h][c] = m0;
  __syncthreads();
  if (h == 0) {
    float m = sh[0][c];
#pragma unroll
    for (int i = 1; i < 8; ++i) m = fmaxf(m, sh[i][c]);
    pooled[(size_t)g * FC + c] = (end > beg) ? m : 0.f;
  }
}

// ---- BN-apply on pooled ----
__global__ void k_poolbn(const float* __restrict__ pooled, const float* __restrict__ colsum,
                         const float* __restrict__ colsumsq, const int* __restrict__ gstart,
                         const float* __restrict__ g1, const float* __restrict__ bt1,
                         float* __restrict__ pbn) {
  int idx = blockIdx.x * 256 + threadIdx.x;
  if (idx < NG * FC) {
    int g = idx / FC, c = idx % FC;
    float m = colsum[c] * (1.f / NN);
    float var = colsumsq[c] * (1.f / NN) - m * m;
    float rs = rsqrtf(var + BNEPS);
    float v = (gstart[g + 1] > gstart[g]) ? (g1[c] * (pooled[idx] - m) * rs + bt1[c]) : 0.f;
    pbn[idx] = v;
  }
}

// ---- small MLP block ----
__global__ __launch_bounds__(256) void k_mlp(const float* __restrict__ X, int ncol,
                                             const float* __restrict__ W,
                                             const float* __restrict__ b,
                                             const float* __restrict__ g,
                                             const float* __restrict__ bt,
                                             float* __restrict__ out) {
  int c = blockIdx.x, t = threadIdx.x;
  __shared__ float vals[NG];
  __shared__ float red[256], redq[256];
  __shared__ float wc[FC];
  if (t < FC) wc[t] = W[(size_t)t * ncol + c];
  __syncthreads();
  float psum = 0.f, psq = 0.f;
  for (int r = t; r < NG; r += 256) {
    float acc = b[c];
#pragma unroll
    for (int k = 0; k < FC; ++k) acc += X[(size_t)r * FC + k] * wc[k];
    float v = fmaxf(acc, 0.f);
    vals[r] = v;
    psum += v;
    psq += v * v;
  }
  red[t] = psum;
  redq[t] = psq;
  __syncthreads();
  for (int s = 128; s > 0; s >>= 1) {
    if (t < s) { red[t] += red[t + s]; redq[t] += redq[t + s]; }
    __syncthreads();
  }
  float m = red[0] * (1.f / NG);
  float var = redq[0] * (1.f / NG) - m * m;
  float rs = rsqrtf(var + BNEPS);
  float gg = g[c], bb = bt[c];
  for (int r = t; r < NG; r += 256) out[(size_t)r * ncol + c] = gg * (vals[r] - m) * rs + bb;
}

extern "C" void kernel_launch(void* const* d_in, const int* in_sizes, int n_in,
                              void* d_out, int out_size, void* d_ws, size_t ws_size,
                              hipStream_t stream) {
  const float* x    = (const float*)d_in[0];
  const int* ei     = (const int*)d_in[1];
  const int* src    = ei;
  const int* dst    = ei + NE;
  const int* batch  = (const int*)d_in[2];
  const float* W1   = (const float*)d_in[3];
  const float* b1   = (const float*)d_in[4];
  const float* W2   = (const float*)d_in[5];
  const float* b2   = (const float*)d_in[6];
  const float* l1W  = (const float*)d_in[7];
  const float* l1b  = (const float*)d_in[8];
  const float* l1g  = (const float*)d_in[9];
  const float* l1bt = (const float*)d_in[10];
  const float* m1W  = (const float*)d_in[11];
  const float* m1b  = (const float*)d_in[12];
  const float* m1g  = (const float*)d_in[13];
  const float* m1bt = (const float*)d_in[14];
  const float* m2W  = (const float*)d_in[15];
  const float* m2b  = (const float*)d_in[16];
  const float* m2g  = (const float*)d_in[17];
  const float* m2bt = (const float*)d_in[18];
  float* out = (float*)d_out;

  float* ws = (float*)d_ws;
  // layout (float indices, all 16B-aligned) — R13 layout
  const size_t o_csum   = 0;          // 128
  const size_t o_csq    = 128;        // 128  (memset 256 floats)
  const size_t o_dinv   = 256;        // 100352
  const size_t o_gstart = 100608;     // 520 (NG+1)
  const size_t o_offs   = 101128;     // 100360 (NN+1 ints)
  const size_t o_offs2  = 201488;     // region 306352 wide; pooled/pbn/h3 alias later
  const size_t o_bsum   = 507840;     // 304
  const size_t o_packed = 508144;     // 3,200,000 ints  <- y(f32, 9.6M) aliases [packed, hcat)
  const size_t o_h1sh   = 3708144;    // 1,600,000 (NN*32 fp16)
  const size_t o_x1sh   = 5308144;    // 1,600,000 (NN*32 fp16)
  const size_t o_csr    = 6908144;    // 3,200,000 ints
  const size_t o_hcat   = 10108144;   // 9,600,000 -> total 19,708,144 floats (78.8 MB)

  float* csum     = ws + o_csum;
  float* csq      = ws + o_csq;
  float* dinv     = ws + o_dinv;
  int* gstart     = (int*)(ws + o_gstart);
  int* offs       = (int*)(ws + o_offs);
  unsigned* offs2 = (unsigned*)(ws + o_offs2);
  unsigned* bsum  = (unsigned*)(ws + o_bsum);
  int* packed     = (int*)(ws + o_packed);
  __half* h1sh    = (__half*)(ws + o_h1sh);
  uint* x1sh      = (uint*)(ws + o_x1sh);
  int* csr        = (int*)(ws + o_csr);
  float* hcat     = ws + o_hcat;
  float* y        = ws + o_packed;           // alias: packed/h1sh/x1sh/csr dead by lin1
  float* pooled   = ws + o_offs2;            // alias: offs2 dead after bsort
  float* pbn      = ws + o_offs2 + 49152;
  float* h3       = ws + o_offs2 + 98304;

  hipMemsetAsync(ws, 0, 256 * sizeof(float), stream);  // csum + csq

  k_hist<<<NBLK, 256, 0, stream>>>(dst, offs2);
  k_scan1<<<SCAN_NB, 256, 0, stream>>>(offs2, SCAN_N, bsum);
  k_scan2<<<1, 512, 0, stream>>>(bsum, SCAN_NB);
  k_scan3<<<(SCAN_N + 255) / 256, 256, 0, stream>>>(offs2, SCAN_N, bsum, NE);
  k_binwrite<<<NBLK, 256, 0, stream>>>(src, dst, offs2, packed);
  k_bsort<<<NBUK, 256, 0, stream>>>(packed, offs2, csr, offs, dinv);
  k_gbound<<<(NN + 255) / 256, 256, 0, stream>>>(batch, gstart);

  k_gemm1<<<(NN + 63) / 64, 256, 0, stream>>>(x, W1, dinv, h1sh);
  // gather1: x1 -> hcat[:,0:32] (+b1, f32); x1sh = fp16(x1*dinv)
  k_gather1<<<NN / 4, 256, 0, stream>>>((const ushort*)h1sh, offs, csr, dinv, b1, hcat, x1sh);
  // gather2+gemm2 fused: hcat[:,32:96] = (Shat*x1s)@W2 + b2
  k_gather2f<<<NN / 4, 256, 0, stream>>>((const ushort*)x1sh, offs, csr, dinv, W2, b2, hcat);

  k_lin1<<<(NN + 63) / 64, 384, 0, stream>>>(hcat, l1W, l1b, y, csum, csq);
  k_pool<<<NG, 768, 0, stream>>>(y, gstart, pooled);
  k_poolbn<<<(NG * FC + 255) / 256, 256, 0, stream>>>(pooled, csum, csq, gstart, l1g, l1bt, pbn);

  k_mlp<<<FC, 256, 0, stream>>>(pbn, FC, m1W, m1b, m1g, m1bt, h3);
  k_mlp<<<NC, 256, 0, stream>>>(h3, NC, m2W, m2b, m2g, m2bt, out);
}

// Round 17
// 299.293 us; speedup vs baseline: 1.1537x; 1.0436x over previous
//
#include <hip/hip_runtime.h>
#include <hip/hip_fp16.h>

#define NN 100000
#define NE 3200000
#define NG 512
#define DIN 128
#define F1 32
#define F2 64
#define FC 96
#define NC 10
#define BNEPS 1e-5f

#define BSH 8                // bucket shift: 256 nodes/bucket
#define NBUK 391             // ceil(NN/256)
#define EPB 16384            // edges per block in hist/binwrite
#define NBLK 196             // ceil(NE/EPB)
#define SCAN_N (NBUK * NBLK) // 76636
#define SCAN_NB ((SCAN_N + 1023) / 1024)  // 75

typedef unsigned int uint;

__device__ __forceinline__ void atomAddF(float* p, float v) { unsafeAtomicAdd(p, v); }
__device__ __forceinline__ float2 h2f(uint u) {
  __half2 h = *reinterpret_cast<__half2*>(&u);
  return __half22float2(h);
}
__device__ __forceinline__ uint f2h2(float a, float b) {
  __half2 h = __floats2half2_rn(a, b);
  return *reinterpret_cast<uint*>(&h);
}

// ---- per-block bucket histogram (int4 edge reads) ----
__global__ __launch_bounds__(256) void k_hist(const int* __restrict__ dst,
                                              unsigned* __restrict__ bhist) {
  __shared__ unsigned h[NBUK];
  int t = threadIdx.x, b = blockIdx.x;
  for (int i = t; i < NBUK; i += 256) h[i] = 0;
  __syncthreads();
  int beg = b * EPB, end = min(beg + EPB, NE);
  for (int e = beg + t * 4; e < end; e += 1024) {
    int4 d4 = *(const int4*)&dst[e];
    atomicAdd(&h[d4.x >> BSH], 1u);
    atomicAdd(&h[d4.y >> BSH], 1u);
    atomicAdd(&h[d4.z >> BSH], 1u);
    atomicAdd(&h[d4.w >> BSH], 1u);
  }
  __syncthreads();
  for (int i = t; i < NBUK; i += 256) bhist[(size_t)i * NBLK + b] = h[i];
}

// ---- generic 3-phase exclusive scan (in place) ----
__global__ __launch_bounds__(256) void k_scan1(unsigned* __restrict__ data, int n,
                                               unsigned* __restrict__ bsum) {
  __shared__ unsigned ts[256];
  int b = blockIdx.x, t = threadIdx.x;
  int base = b * 1024 + t * 4;
  unsigned v0 = 0, v1 = 0, v2 = 0, v3 = 0;
  if (base + 3 < n) {
    uint4 u = *(const uint4*)&data[base];
    v0 = u.x; v1 = u.y; v2 = u.z; v3 = u.w;
  } else {
    if (base < n) v0 = data[base];
    if (base + 1 < n) v1 = data[base + 1];
    if (base + 2 < n) v2 = data[base + 2];
    if (base + 3 < n) v3 = data[base + 3];
  }
  unsigned s = v0 + v1 + v2 + v3;
  ts[t] = s;
  __syncthreads();
  for (int d = 1; d < 256; d <<= 1) {
    unsigned add = (t >= d) ? ts[t - d] : 0u;
    __syncthreads();
    ts[t] += add;
    __syncthreads();
  }
  unsigned run = ts[t] - s;
  if (t == 255) bsum[b] = ts[255];
  if (base < n) data[base] = run;
  run += v0;
  if (base + 1 < n) data[base + 1] = run;
  run += v1;
  if (base + 2 < n) data[base + 2] = run;
  run += v2;
  if (base + 3 < n) data[base + 3] = run;
}

__global__ void k_scan2(unsigned* __restrict__ bsum, int nb) {
  __shared__ unsigned ts[512];
  int t = threadIdx.x;
  unsigned v = (t < nb) ? bsum[t] : 0u;
  ts[t] = v;
  __syncthreads();
  for (int d = 1; d < 512; d <<= 1) {
    unsigned a = (t >= d) ? ts[t - d] : 0u;
    __syncthreads();
    ts[t] += a;
    __syncthreads();
  }
  if (t < nb) bsum[t] = ts[t] - v;
}

__global__ void k_scan3(unsigned* __restrict__ data, int n, const unsigned* __restrict__ bsum,
                        int total) {
  int i = blockIdx.x * 256 + threadIdx.x;
  if (i < n) data[i] += bsum[i >> 10];
  if (i == 0) data[n] = (unsigned)total;
}

// ---- bin-write: packed[pos] = (src<<8)|dstlo, grouped by bucket (int4 reads) ----
__global__ __launch_bounds__(256) void k_binwrite(const int* __restrict__ src,
                                                  const int* __restrict__ dst,
                                                  const unsigned* __restrict__ offs2,
                                                  int* __restrict__ packed) {
  __shared__ unsigned cur[NBUK];
  int t = threadIdx.x, b = blockIdx.x;
  for (int i = t; i < NBUK; i += 256) cur[i] = offs2[(size_t)i * NBLK + b];
  __syncthreads();
  int beg = b * EPB, end = min(beg + EPB, NE);
  for (int e = beg + t * 4; e < end; e += 1024) {
    int4 d4 = *(const int4*)&dst[e];
    int4 s4 = *(const int4*)&src[e];
    unsigned p0 = atomicAdd(&cur[d4.x >> BSH], 1u);
    packed[p0] = (s4.x << BSH) | (d4.x & 255);
    unsigned p1 = atomicAdd(&cur[d4.y >> BSH], 1u);
    packed[p1] = (s4.y << BSH) | (d4.y & 255);
    unsigned p2 = atomicAdd(&cur[d4.z >> BSH], 1u);
    packed[p2] = (s4.z << BSH) | (d4.z & 255);
    unsigned p3 = atomicAdd(&cur[d4.w >> BSH], 1u);
    packed[p3] = (s4.w << BSH) | (d4.w & 255);
  }
}

// ---- bucket counting-sort (256 nodes/bucket) -> per-node CSR + offs + dinv ----
__global__ __launch_bounds__(256) void k_bsort(const int* __restrict__ packed,
                                               const unsigned* __restrict__ offs2,
                                               int* __restrict__ csr,
                                               int* __restrict__ offs,
                                               float* __restrict__ dinv) {
  int buk = blockIdx.x, t = threadIdx.x;
  __shared__ unsigned cnt[256];
  __shared__ int cur[256];
  __shared__ unsigned wsum[4];
  cnt[t] = 0;
  __syncthreads();
  unsigned beg = offs2[(size_t)buk * NBLK], end = offs2[(size_t)(buk + 1) * NBLK];
  for (unsigned j = beg + t; j < end; j += 256) atomicAdd(&cnt[packed[j] & 255], 1u);
  __syncthreads();
  unsigned v = cnt[t];
  unsigned inc = v;
#pragma unroll
  for (int d = 1; d < 64; d <<= 1) {
    unsigned o = __shfl_up(inc, d, 64);
    if ((t & 63) >= d) inc += o;
  }
  int wv = t >> 6;
  if ((t & 63) == 63) wsum[wv] = inc;
  __syncthreads();
  unsigned woff = 0;
  for (int i = 0; i < wv; ++i) woff += wsum[i];
  unsigned ex = woff + inc - v;  // exclusive prefix within bucket
  cur[t] = (int)(beg + ex);
  int node = (buk << BSH) + t;
  if (node < NN) {
    offs[node] = (int)(beg + ex);
    dinv[node] = rsqrtf((float)v + 1.0f);
  } else if (node == NN) {
    offs[NN] = (int)(beg + ex);  // == NE
  }
  __syncthreads();
  for (unsigned j = beg + t; j < end; j += 256) {
    int p = packed[j];
    int pos = atomicAdd(&cur[p & 255], 1);
    csr[pos] = p >> BSH;
  }
}

// ---- graph boundaries from sorted batch ----
__global__ void k_gbound(const int* __restrict__ batch, int* __restrict__ gstart) {
  int i = blockIdx.x * 256 + threadIdx.x;
  if (i >= NN) return;
  int b = batch[i], p = i ? batch[i - 1] : -1;
  for (int g = p + 1; g <= b; ++g) gstart[g] = i;
  if (i == NN - 1)
    for (int g = b + 1; g <= NG; ++g) gstart[g] = NN;
}

// ---- gemm1: h1sh = fp16((x @ W1) * dinv)  [NN,128]@[128,32] ----
__global__ __launch_bounds__(256) void k_gemm1(const float* __restrict__ x,
                                               const float* __restrict__ W,
                                               const float* __restrict__ dinv,
                                               __half* __restrict__ h1sh) {
  __shared__ __align__(16) float Ws[DIN * F1];     // 16 KB, [k][c] row-major
  __shared__ __align__(16) float xs[64][DIN + 4];  // 33 KB
  int t = threadIdx.x;
  for (int i = t; i < DIN * F1 / 4; i += 256)
    *(float4*)&Ws[i * 4] = *(const float4*)&W[i * 4];
  int row0 = blockIdx.x * 64;
  for (int i = t; i < 64 * 32; i += 256) {
    int r = i >> 5, q = i & 31;
    int row = row0 + r;
    float4 v = (row < NN) ? *(const float4*)&x[(size_t)row * DIN + q * 4]
                          : make_float4(0.f, 0.f, 0.f, 0.f);
    *(float4*)&xs[r][q * 4] = v;
  }
  __syncthreads();
  int cg = t & 7, rg = t >> 3;   // 8 col-groups x 32 row-groups
  int c0 = cg * 4, r0 = rg * 2;
  float acc[2][4];
#pragma unroll
  for (int i = 0; i < 2; ++i)
#pragma unroll
    for (int j = 0; j < 4; ++j) acc[i][j] = 0.f;
#pragma unroll 4
  for (int k = 0; k < DIN; k += 4) {
    float4 xv0 = *(float4*)&xs[r0][k];
    float4 xv1 = *(float4*)&xs[r0 + 1][k];
    float4 wf[4];
#pragma unroll
    for (int m = 0; m < 4; ++m) wf[m] = *(float4*)&Ws[(k + m) * F1 + c0];
    const float* x0 = (const float*)&xv0;
    const float* x1 = (const float*)&xv1;
#pragma unroll
    for (int m = 0; m < 4; ++m) {
      const float* wp = (const float*)&wf[m];
#pragma unroll
      for (int j = 0; j < 4; ++j) {
        acc[0][j] += x0[m] * wp[j];
        acc[1][j] += x1[m] * wp[j];
      }
    }
  }
#pragma unroll
  for (int i = 0; i < 2; ++i) {
    int row = row0 + r0 + i;
    if (row < NN) {
      float dv = dinv[row];
      uint2 o;
      o.x = f2h2(acc[i][0] * dv, acc[i][1] * dv);
      o.y = f2h2(acc[i][2] * dv, acc[i][3] * dv);
      *(uint2*)&h1sh[(size_t)row * F1 + c0] = o;
    }
  }
}

// ---- gather core: 2-deep accumulate over [beg,end) (R13 measured-best) ----
__device__ __forceinline__ void gath2(const ushort* __restrict__ hs,
                                      const int* __restrict__ csr,
                                      int beg, int end, int slot, int f4,
                                      float& ax, float& ay, float& az, float& aw) {
  int j = beg + slot;
  for (; j + 8 < end; j += 16) {
    int s0 = csr[j], s1 = csr[j + 8];
    uint2 u0 = *(const uint2*)&hs[(size_t)s0 * F1 + f4];
    uint2 u1 = *(const uint2*)&hs[(size_t)s1 * F1 + f4];
    float2 a0 = h2f(u0.x), b0 = h2f(u0.y), a1 = h2f(u1.x), b1 = h2f(u1.y);
    ax += a0.x + a1.x; ay += a0.y + a1.y;
    az += b0.x + b1.x; aw += b0.y + b1.y;
  }
  if (j < end) {
    int s0 = csr[j];
    uint2 u0 = *(const uint2*)&hs[(size_t)s0 * F1 + f4];
    float2 a0 = h2f(u0.x), b0 = h2f(u0.y);
    ax += a0.x; ay += a0.y; az += b0.x; aw += b0.y;
  }
}

// ---- gather1: x1 = dinv*(h1s[node]+sum h1s[src]) + b1 -> hcat[:,0:32] (f32)
//      x1sh = fp16(x1 * dinv)
__global__ __launch_bounds__(256) void k_gather1(const ushort* __restrict__ hs,
                                                 const int* __restrict__ offs,
                                                 const int* __restrict__ csr,
                                                 const float* __restrict__ dinv,
                                                 const float* __restrict__ bias,
                                                 float* __restrict__ out1,
                                                 uint* __restrict__ out2) {
  int node = blockIdx.x * 4 + (threadIdx.x >> 6);  // NN%4==0
  int lane = threadIdx.x & 63;
  int slot = lane >> 3, f4 = (lane & 7) * 4;
  int beg = offs[node], end = offs[node + 1];
  float ax = 0.f, ay = 0.f, az = 0.f, aw = 0.f;
  gath2(hs, csr, beg, end, slot, f4, ax, ay, az, aw);
#pragma unroll
  for (int m = 8; m < 64; m <<= 1) {
    ax += __shfl_xor(ax, m, 64); ay += __shfl_xor(ay, m, 64);
    az += __shfl_xor(az, m, 64); aw += __shfl_xor(aw, m, 64);
  }
  if (slot == 0) {
    float dv = dinv[node];
    uint2 su = *(const uint2*)&hs[(size_t)node * F1 + f4];
    float2 sa = h2f(su.x), sb = h2f(su.y);
    float4 bb = *(const float4*)&bias[f4];
    float vx = dv * (sa.x + ax) + bb.x;
    float vy = dv * (sa.y + ay) + bb.y;
    float vz = dv * (sb.x + az) + bb.z;
    float vw = dv * (sb.y + aw) + bb.w;
    *(float4*)&out1[(size_t)node * FC + f4] = make_float4(vx, vy, vz, vw);
    uint2 o;
    o.x = f2h2(vx * dv, vy * dv);
    o.y = f2h2(vz * dv, vw * dv);
    *(uint2*)&out2[(size_t)node * 16 + (f4 >> 1)] = o;
  }
}

// ---- gather2 fused with W2 matvec: hcat[:,32:96] = (Shat*x1s_row) @ W2 + b2 (f32) ----
__global__ __launch_bounds__(256) void k_gather2f(const ushort* __restrict__ hs,
                                                  const int* __restrict__ offs,
                                                  const int* __restrict__ csr,
                                                  const float* __restrict__ dinv,
                                                  const float* __restrict__ W2,
                                                  const float* __restrict__ b2,
                                                  float* __restrict__ hcat) {
  __shared__ float rowbuf[4][F1];
  int wv = threadIdx.x >> 6;
  int node = blockIdx.x * 4 + wv;  // NN%4==0
  int lane = threadIdx.x & 63;
  int slot = lane >> 3, f4 = (lane & 7) * 4;
  int beg = offs[node], end = offs[node + 1];
  float ax = 0.f, ay = 0.f, az = 0.f, aw = 0.f;
  gath2(hs, csr, beg, end, slot, f4, ax, ay, az, aw);
#pragma unroll
  for (int m = 8; m < 64; m <<= 1) {
    ax += __shfl_xor(ax, m, 64); ay += __shfl_xor(ay, m, 64);
    az += __shfl_xor(az, m, 64); aw += __shfl_xor(aw, m, 64);
  }
  if (slot == 0) {
    float dv = dinv[node];
    uint2 su = *(const uint2*)&hs[(size_t)node * F1 + f4];
    float2 sa = h2f(su.x), sb = h2f(su.y);
    *(float4*)&rowbuf[wv][f4] = make_float4(
        dv * (sa.x + ax), dv * (sa.y + ay),
        dv * (sb.x + az), dv * (sb.y + aw));
  }
  __syncthreads();
  const float* row = rowbuf[wv];
  float acc = b2[lane];
#pragma unroll
  for (int k = 0; k < F1; ++k) acc += row[k] * W2[k * F2 + lane];
  hcat[(size_t)node * FC + F1 + lane] = acc;
}

// ---- lin1 v6: 64x96 tile, K split (32.5 KB LDS, 4 blocks/CU); y out fp16 ----
__global__ __launch_bounds__(384) void k_lin1(const float* __restrict__ hcat,
                                              const float* __restrict__ W,
                                              const float* __restrict__ b,
                                              uint* __restrict__ yu,
                                              float* __restrict__ colsum,
                                              float* __restrict__ colsumsq) {
  __shared__ __align__(16) float lds[8128];  // 32.5 KB: sW[48][100] + sX[64][52]
  float* sW = lds;          // [48][100]
  float* sX = lds + 4800;   // [64][52]
  int t = threadIdx.x;
  int row0 = blockIdx.x * 64;
  int tx = t % 24, ty = t / 24;
  int c0 = tx * 4, r0 = ty * 4;
  float acc[4][4];
#pragma unroll
  for (int i = 0; i < 4; ++i)
#pragma unroll
    for (int j = 0; j < 4; ++j) acc[i][j] = 0.f;
#pragma unroll
  for (int kc = 0; kc < 2; ++kc) {
    for (int i = t; i < 48 * 24; i += 384) {
      int k = i / 24, cq = (i % 24) * 4;
      float4 v = *(const float4*)&W[(kc * 48 + k) * FC + cq];
      *(float4*)&sW[k * 100 + cq] = v;
    }
    for (int i = t; i < 64 * 12; i += 384) {
      int r = i / 12, q = (i % 12) * 4;
      int row = row0 + r;
      float4 v = (row < NN) ? *(const float4*)&hcat[(size_t)row * FC + kc * 48 + q]
                            : make_float4(0.f, 0.f, 0.f, 0.f);
      *(float4*)&sX[r * 52 + q] = v;
    }
    __syncthreads();
#pragma unroll 4
    for (int k0 = 0; k0 < 48; k0 += 4) {
      float4 xf[4], wf[4];
#pragma unroll
      for (int i = 0; i < 4; ++i) xf[i] = *(float4*)&sX[(r0 + i) * 52 + k0];
#pragma unroll
      for (int m = 0; m < 4; ++m) wf[m] = *(float4*)&sW[(k0 + m) * 100 + c0];
#pragma unroll
      for (int i = 0; i < 4; ++i) {
        const float* xp = (const float*)&xf[i];
#pragma unroll
        for (int m = 0; m < 4; ++m) {
          const float* wp = (const float*)&wf[m];
#pragma unroll
          for (int j = 0; j < 4; ++j) acc[i][j] += xp[m] * wp[j];
        }
      }
    }
    __syncthreads();
  }
  float4 bb = *(const float4*)&b[c0];
  const float* bp = (const float*)&bb;
  float colp[4] = {0.f, 0.f, 0.f, 0.f}, colq[4] = {0.f, 0.f, 0.f, 0.f};
#pragma unroll
  for (int i = 0; i < 4; ++i) {
    int row = row0 + r0 + i;
    if (row < NN) {
      float v0 = fmaxf(acc[i][0] + bp[0], 0.f);
      float v1 = fmaxf(acc[i][1] + bp[1], 0.f);
      float v2 = fmaxf(acc[i][2] + bp[2], 0.f);
      float v3 = fmaxf(acc[i][3] + bp[3], 0.f);
      uint2 o;
      o.x = f2h2(v0, v1);
      o.y = f2h2(v2, v3);
      *(uint2*)&yu[(size_t)row * 48 + tx * 2] = o;
      colp[0] += v0; colp[1] += v1; colp[2] += v2; colp[3] += v3;
      colq[0] += v0 * v0; colq[1] += v1 * v1; colq[2] += v2 * v2; colq[3] += v3 * v3;
    }
  }
  float* ps = sW;
  float* pq = sW + 1536;
  *(float4*)&ps[ty * 96 + c0] = make_float4(colp[0], colp[1], colp[2], colp[3]);
  *(float4*)&pq[ty * 96 + c0] = make_float4(colq[0], colq[1], colq[2], colq[3]);
  __syncthreads();
  if (t < 96) {
    float s = 0.f, s2 = 0.f;
#pragma unroll
    for (int i = 0; i < 16; ++i) { s += ps[i * 96 + t]; s2 += pq[i * 96 + t]; }
    atomAddF(&colsum[t], s);
    atomAddF(&colsumsq[t], s2);
  }
}

// ---- per-graph max pool (batch sorted), fp16 y: 16 rows in flight ----
__global__ __launch_bounds__(768) void k_pool(const uint* __restrict__ y,
                                              const int* __restrict__ gstart,
                                              float* __restrict__ pooled) {
  int g = blockIdx.x, t = threadIdx.x;
  int c = t % 48, h = t / 48;  // 16 rows in flight, each uint = 2 cols
  int beg = gstart[g], end = gstart[g + 1];
  float m0 = 0.f, m1 = 0.f;
  for (int r = beg + h; r < end; r += 16) {
    float2 v = h2f(y[(size_t)r * 48 + c]);
    m0 = fmaxf(m0, v.x);
    m1 = fmaxf(m1, v.y);
  }
  __shared__ float sh[2][16][48];
  sh[0][h][c] = m0;
  sh[1][h][c] = m1;
  __syncthreads();
  if (t < 96) {
    int cc = t >> 1, par = t & 1;
    float m = sh[par][0][cc];
#pragma unroll
    for (int i = 1; i < 16; ++i) m = fmaxf(m, sh[par][i][cc]);
    pooled[(size_t)g * FC + t] = (end > beg) ? m : 0.f;
  }
}

// ---- BN-apply on pooled ----
__global__ void k_poolbn(const float* __restrict__ pooled, const float* __restrict__ colsum,
                         const float* __restrict__ colsumsq, const int* __restrict__ gstart,
                         const float* __restrict__ g1, const float* __restrict__ bt1,
                         float* __restrict__ pbn) {
  int idx = blockIdx.x * 256 + threadIdx.x;
  if (idx < NG * FC) {
    int g = idx / FC, c = idx % FC;
    float m = colsum[c] * (1.f / NN);
    float var = colsumsq[c] * (1.f / NN) - m * m;
    float rs = rsqrtf(var + BNEPS);
    float v = (gstart[g + 1] > gstart[g]) ? (g1[c] * (pooled[idx] - m) * rs + bt1[c]) : 0.f;
    pbn[idx] = v;
  }
}

// ---- small MLP block ----
__global__ __launch_bounds__(256) void k_mlp(const float* __restrict__ X, int ncol,
                                             const float* __restrict__ W,
                                             const float* __restrict__ b,
                                             const float* __restrict__ g,
                                             const float* __restrict__ bt,
                                             float* __restrict__ out) {
  int c = blockIdx.x, t = threadIdx.x;
  __shared__ float vals[NG];
  __shared__ float red[256], redq[256];
  __shared__ float wc[FC];
  if (t < FC) wc[t] = W[(size_t)t * ncol + c];
  __syncthreads();
  float psum = 0.f, psq = 0.f;
  for (int r = t; r < NG; r += 256) {
    float acc = b[c];
#pragma unroll
    for (int k = 0; k < FC; ++k) acc += X[(size_t)r * FC + k] * wc[k];
    float v = fmaxf(acc, 0.f);
    vals[r] = v;
    psum += v;
    psq += v * v;
  }
  red[t] = psum;
  redq[t] = psq;
  __syncthreads();
  for (int s = 128; s > 0; s >>= 1) {
    if (t < s) { red[t] += red[t + s]; redq[t] += redq[t + s]; }
    __syncthreads();
  }
  float m = red[0] * (1.f / NG);
  float var = redq[0] * (1.f / NG) - m * m;
  float rs = rsqrtf(var + BNEPS);
  float gg = g[c], bb = bt[c];
  for (int r = t; r < NG; r += 256) out[(size_t)r * ncol + c] = gg * (vals[r] - m) * rs + bb;
}

extern "C" void kernel_launch(void* const* d_in, const int* in_sizes, int n_in,
                              void* d_out, int out_size, void* d_ws, size_t ws_size,
                              hipStream_t stream) {
  const float* x    = (const float*)d_in[0];
  const int* ei     = (const int*)d_in[1];
  const int* src    = ei;
  const int* dst    = ei + NE;
  const int* batch  = (const int*)d_in[2];
  const float* W1   = (const float*)d_in[3];
  const float* b1   = (const float*)d_in[4];
  const float* W2   = (const float*)d_in[5];
  const float* b2   = (const float*)d_in[6];
  const float* l1W  = (const float*)d_in[7];
  const float* l1b  = (const float*)d_in[8];
  const float* l1g  = (const float*)d_in[9];
  const float* l1bt = (const float*)d_in[10];
  const float* m1W  = (const float*)d_in[11];
  const float* m1b  = (const float*)d_in[12];
  const float* m1g  = (const float*)d_in[13];
  const float* m1bt = (const float*)d_in[14];
  const float* m2W  = (const float*)d_in[15];
  const float* m2b  = (const float*)d_in[16];
  const float* m2g  = (const float*)d_in[17];
  const float* m2bt = (const float*)d_in[18];
  float* out = (float*)d_out;

  float* ws = (float*)d_ws;
  // layout (float indices, all 16B-aligned) — R13 layout
  const size_t o_csum   = 0;          // 128
  const size_t o_csq    = 128;        // 128  (memset 256 floats)
  const size_t o_dinv   = 256;        // 100352
  const size_t o_gstart = 100608;     // 520 (NG+1)
  const size_t o_offs   = 101128;     // 100360 (NN+1 ints)
  const size_t o_offs2  = 201488;     // region 306352 wide; pooled/pbn/h3 alias later
  const size_t o_bsum   = 507840;     // 304
  const size_t o_packed = 508144;     // 3,200,000 ints  <- yu(fp16, 4.8M uints) aliases packed+h1sh
  const size_t o_h1sh   = 3708144;    // 1,600,000 (NN*32 fp16)
  const size_t o_x1sh   = 5308144;    // 1,600,000 (NN*32 fp16)
  const size_t o_csr    = 6908144;    // 3,200,000 ints
  const size_t o_hcat   = 10108144;   // 9,600,000 -> total 19,708,144 floats (78.8 MB)

  float* csum     = ws + o_csum;
  float* csq      = ws + o_csq;
  float* dinv     = ws + o_dinv;
  int* gstart     = (int*)(ws + o_gstart);
  int* offs       = (int*)(ws + o_offs);
  unsigned* offs2 = (unsigned*)(ws + o_offs2);
  unsigned* bsum  = (unsigned*)(ws + o_bsum);
  int* packed     = (int*)(ws + o_packed);
  __half* h1sh    = (__half*)(ws + o_h1sh);
  uint* x1sh      = (uint*)(ws + o_x1sh);
  int* csr        = (int*)(ws + o_csr);
  float* hcat     = ws + o_hcat;
  uint* yu        = (uint*)(ws + o_packed);  // alias: packed+h1sh dead by lin1 (needs 4.8M)
  float* pooled   = ws + o_offs2;            // alias: offs2 dead after bsort
  float* pbn      = ws + o_offs2 + 49152;
  float* h3       = ws + o_offs2 + 98304;

  hipMemsetAsync(ws, 0, 256 * sizeof(float), stream);  // csum + csq

  k_hist<<<NBLK, 256, 0, stream>>>(dst, offs2);
  k_scan1<<<SCAN_NB, 256, 0, stream>>>(offs2, SCAN_N, bsum);
  k_scan2<<<1, 512, 0, stream>>>(bsum, SCAN_NB);
  k_scan3<<<(SCAN_N + 255) / 256, 256, 0, stream>>>(offs2, SCAN_N, bsum, NE);
  k_binwrite<<<NBLK, 256, 0, stream>>>(src, dst, offs2, packed);
  k_bsort<<<NBUK, 256, 0, stream>>>(packed, offs2, csr, offs, dinv);
  k_gbound<<<(NN + 255) / 256, 256, 0, stream>>>(batch, gstart);

  k_gemm1<<<(NN + 63) / 64, 256, 0, stream>>>(x, W1, dinv, h1sh);
  // gather1: x1 -> hcat[:,0:32] (+b1, f32); x1sh = fp16(x1*dinv)
  k_gather1<<<NN / 4, 256, 0, stream>>>((const ushort*)h1sh, offs, csr, dinv, b1, hcat, x1sh);
  // gather2+gemm2 fused: hcat[:,32:96] = (Shat*x1s)@W2 + b2
  k_gather2f<<<NN / 4, 256, 0, stream>>>((const ushort*)x1sh, offs, csr, dinv, W2, b2, hcat);

  k_lin1<<<(NN + 63) / 64, 384, 0, stream>>>(hcat, l1W, l1b, yu, csum, csq);
  k_pool<<<NG, 768, 0, stream>>>(yu, gstart, pooled);
  k_poolbn<<<(NG * FC + 255) / 256, 256, 0, stream>>>(pooled, csum, csq, gstart, l1g, l1bt, pbn);

  k_mlp<<<FC, 256, 0, stream>>>(pbn, FC, m1W, m1b, m1g, m1bt, h3);
  k_mlp<<<NC, 256, 0, stream>>>(h3, NC, m2W, m2b, m2g, m2bt, out);
}